// Round 11
// baseline (1367.494 us; speedup 1.0000x reference)
//
#include <hip/hip_runtime.h>
#include <hip/hip_bf16.h>
#include <hip/hip_fp16.h>

#define HH 32
#define HH2 64
#define NRBF_ 20
#define NL 5
#define NNN 256
#define KBW 8
#define PGN 4024
#define TTAB 4096
constexpr int NNODE = 128768;
constexpr int NHALF = NNODE / 2;          // 64384
constexpr int N2 = NNODE * 2;             // 257536 virtual rows (dst*2 + srchalf)
constexpr int NEDGE = 2060288;
constexpr float BNEPS = 1e-5f;
constexpr float PI_F = 3.14159265358979323846f;

// ---------------- node RBF embed -> fp16 h
__global__ void __launch_bounds__(256) k_node_embed(const float* __restrict__ x3d,
                                                    const float* __restrict__ wlen,
                                                    const float* __restrict__ blen,
                                                    __half* __restrict__ hbuf) {
  __shared__ float wl[NRBF_ * HH];
  __shared__ float bl[HH];
  int t = threadIdx.x;
  for (int j = t; j < NRBF_ * HH; j += 256) wl[j] = wlen[j];
  if (t < HH) bl[t] = blen[t];
  __syncthreads();
  int idx = blockIdx.x * 256 + t;
  int n = idx >> 5, c = idx & 31;
  float x = x3d[n];
  float acc = bl[c];
#pragma unroll
  for (int k = 0; k < NRBF_; ++k) {
    float d = x - 0.1f * (float)k;
    acc = fmaf(__expf(-10.f * d * d), wl[k * HH + c], acc);
  }
  hbuf[idx] = __float2half(acc);
}

// ---------------- ea nearest-neighbor table (4096 rows, fp16)
__global__ void __launch_bounds__(256) k_tab(const float* __restrict__ wang,
                                             const float* __restrict__ bang,
                                             __half* __restrict__ tab) {
  __shared__ float wa[NRBF_ * HH];
  __shared__ float ba[HH];
  int t = threadIdx.x;
  for (int j = t; j < NRBF_ * HH; j += 256) wa[j] = wang[j];
  if (t < HH) ba[t] = bang[t];
  __syncthreads();
  int idx = blockIdx.x * 256 + t;
  int row = idx >> 5, c = idx & 31;
  float ang = (float)row * (PI_F / (float)(TTAB - 1));
  const float step = PI_F / 19.f;
  float acc = ba[c];
#pragma unroll
  for (int k = 0; k < NRBF_; ++k) {
    float d = ang - step * (float)k;
    acc = fmaf(__expf(-10.f * d * d), wa[k * HH + c], acc);
  }
  tab[row * HH + c] = __float2half(acc);
}

// ---------------- histogram over virtual rows dst*2 + (src>=NHALF)
__global__ void __launch_bounds__(256) k_hist(const int* __restrict__ srcA,
                                              const int* __restrict__ dstA,
                                              int* __restrict__ counts) {
  int e = blockIdx.x * 256 + threadIdx.x;
  int bin = dstA[e] * 2 + (srcA[e] >= NHALF ? 1 : 0);
  atomicAdd(&counts[bin], 1);
}

// ---------------- scan step 1 (1006 blocks x 256)
__global__ void __launch_bounds__(256) k_scan1(const int* __restrict__ counts, int* __restrict__ bsum) {
  __shared__ int sd[256];
  int t = threadIdx.x;
  sd[t] = counts[blockIdx.x * 256 + t];
  __syncthreads();
  for (int s = 128; s > 0; s >>= 1) { if (t < s) sd[t] += sd[t + s]; __syncthreads(); }
  if (t == 0) bsum[blockIdx.x] = sd[0];
}

// ---------------- scan step 2 (1 block x 1024, 1006 entries)
__global__ void __launch_bounds__(1024) k_scan2(const int* __restrict__ bsum, int* __restrict__ boff) {
  __shared__ int sd[1024];
  int t = threadIdx.x;
  int v = (t < 1006) ? bsum[t] : 0;
  sd[t] = v;
  __syncthreads();
  for (int off = 1; off < 1024; off <<= 1) {
    int x = (t >= off) ? sd[t - off] : 0;
    __syncthreads();
    sd[t] += x;
    __syncthreads();
  }
  if (t < 1006) boff[t] = sd[t] - v;
}

// ---------------- scan step 3: rowptr2 + cursor2 over N2 virtual rows
__global__ void __launch_bounds__(256) k_scan3(const int* __restrict__ counts, const int* __restrict__ boff,
                                               int* __restrict__ rowptr2, int* __restrict__ cursor2) {
  __shared__ int sd[256];
  int t = threadIdx.x;
  int i = blockIdx.x * 256 + t;
  int v = counts[i];
  sd[t] = v;
  __syncthreads();
  for (int off = 1; off < 256; off <<= 1) {
    int x = (t >= off) ? sd[t - off] : 0;
    __syncthreads();
    sd[t] += x;
    __syncthreads();
  }
  int excl = sd[t] - v + boff[blockIdx.x];
  rowptr2[i] = excl;
  cursor2[i] = excl;
  if (i == N2 - 1) rowptr2[N2] = excl + v;
}

// ---------------- XCD-range-exclusive scatter into (dst, srchalf)-sorted order
__global__ void __launch_bounds__(256) k_scatter(const int* __restrict__ srcA,
                                                 const int* __restrict__ dstA,
                                                 const float* __restrict__ eattr,
                                                 int* __restrict__ cursor2,
                                                 unsigned int* __restrict__ pk) {
  const float angsc = (float)(TTAB - 1) / PI_F;
  int bid = blockIdx.x;
  int x = bid & 7;
  int j = bid >> 3;
  int lo = x * (NNODE / 8);
  int hi = lo + (NNODE / 8);
  int e0 = j * 2048 + threadIdx.x;
#pragma unroll
  for (int k = 0; k < 8; ++k) {
    int e = e0 + k * 256;
    int d = dstA[e];
    if (d >= lo && d < hi) {
      int s = srcA[e];
      int bin = d * 2 + (s >= NHALF ? 1 : 0);
      int pos = atomicAdd(&cursor2[bin], 1);
      unsigned int idx = min((unsigned int)fmaf(eattr[e], angsc, 0.5f), (unsigned int)(TTAB - 1));
      pk[pos] = (unsigned int)s | (idx << 17);
    }
  }
}

// ---------------- shared 8-wide gather-aggregate over an edge range
__device__ __forceinline__ float edge_gather(const __half* __restrict__ hbuf,
                                             const __half* __restrict__ tab,
                                             const unsigned int* __restrict__ pk,
                                             int p0, int p1, int c,
                                             float sc, float sh, float lo) {
  float acc = 0.f;
  int p = p0;
  for (; p + 8 <= p1; p += 8) {
    unsigned int q0 = __builtin_nontemporal_load(&pk[p]);
    unsigned int q1 = __builtin_nontemporal_load(&pk[p + 1]);
    unsigned int q2 = __builtin_nontemporal_load(&pk[p + 2]);
    unsigned int q3 = __builtin_nontemporal_load(&pk[p + 3]);
    unsigned int q4 = __builtin_nontemporal_load(&pk[p + 4]);
    unsigned int q5 = __builtin_nontemporal_load(&pk[p + 5]);
    unsigned int q6 = __builtin_nontemporal_load(&pk[p + 6]);
    unsigned int q7 = __builtin_nontemporal_load(&pk[p + 7]);
    float h0 = __half2float(hbuf[(q0 & 0x1FFFF) * HH + c]);
    float h1 = __half2float(hbuf[(q1 & 0x1FFFF) * HH + c]);
    float h2 = __half2float(hbuf[(q2 & 0x1FFFF) * HH + c]);
    float h3 = __half2float(hbuf[(q3 & 0x1FFFF) * HH + c]);
    float h4 = __half2float(hbuf[(q4 & 0x1FFFF) * HH + c]);
    float h5 = __half2float(hbuf[(q5 & 0x1FFFF) * HH + c]);
    float h6 = __half2float(hbuf[(q6 & 0x1FFFF) * HH + c]);
    float h7 = __half2float(hbuf[(q7 & 0x1FFFF) * HH + c]);
    float e0 = __half2float(tab[(q0 >> 17) * HH + c]);
    float e1 = __half2float(tab[(q1 >> 17) * HH + c]);
    float e2 = __half2float(tab[(q2 >> 17) * HH + c]);
    float e3 = __half2float(tab[(q3 >> 17) * HH + c]);
    float e4 = __half2float(tab[(q4 >> 17) * HH + c]);
    float e5 = __half2float(tab[(q5 >> 17) * HH + c]);
    float e6 = __half2float(tab[(q6 >> 17) * HH + c]);
    float e7 = __half2float(tab[(q7 >> 17) * HH + c]);
    h0 = fmaxf(fmaf(h0, sc, sh), lo); h1 = fmaxf(fmaf(h1, sc, sh), lo);
    h2 = fmaxf(fmaf(h2, sc, sh), lo); h3 = fmaxf(fmaf(h3, sc, sh), lo);
    h4 = fmaxf(fmaf(h4, sc, sh), lo); h5 = fmaxf(fmaf(h5, sc, sh), lo);
    h6 = fmaxf(fmaf(h6, sc, sh), lo); h7 = fmaxf(fmaf(h7, sc, sh), lo);
    acc += fmaxf(h0 + e0, 0.f) + fmaxf(h1 + e1, 0.f) + fmaxf(h2 + e2, 0.f) + fmaxf(h3 + e3, 0.f)
         + fmaxf(h4 + e4, 0.f) + fmaxf(h5 + e5, 0.f) + fmaxf(h6 + e6, 0.f) + fmaxf(h7 + e7, 0.f);
  }
  for (; p < p1; ++p) {
    unsigned int q0 = __builtin_nontemporal_load(&pk[p]);
    float h0 = fmaxf(fmaf(__half2float(hbuf[(q0 & 0x1FFFF) * HH + c]), sc, sh), lo);
    acc += fmaxf(h0 + __half2float(tab[(q0 >> 17) * HH + c]), 0.f);
  }
  return acc;
}

// ---------------- layerA pass 0: low-src edges only (gathers confined to hbuf[0..NHALF))
__global__ void __launch_bounds__(256) k_layerA0(const __half* __restrict__ hbuf,
                                                 const int* __restrict__ rowptr2,
                                                 const unsigned int* __restrict__ pk,
                                                 const __half* __restrict__ tab,
                                                 const float* __restrict__ statsC,
                                                 const float* __restrict__ bng,
                                                 const float* __restrict__ bnb,
                                                 float* __restrict__ partf,
                                                 int l, int relu) {
  __shared__ float affs[HH], affsh[HH];
  int t = threadIdx.x;
  if (t < HH) {
    if (l == 0) { affs[t] = 1.f; affsh[t] = 0.f; }
    else {
      float sum = statsC[(l - 1) * 64 + t], sq = statsC[(l - 1) * 64 + 32 + t];
      float mean = sum / (float)NNODE;
      float var = fmaxf(sq / (float)NNODE - mean * mean, 0.f);
      float s = bng[(l - 1) * HH + t] * rsqrtf(var + BNEPS);
      affs[t] = s; affsh[t] = bnb[(l - 1) * HH + t] - mean * s;
    }
  }
  int g = t >> 5, c = t & 31;
  float lo = relu ? 0.f : -3.4e38f;
  __syncthreads();
  float sc = affs[c], sh = affsh[c];
  int stride = gridDim.x * 8;
  int iters = (NNODE + stride - 1) / stride;
  int n = blockIdx.x * 8 + g;
  for (int it = 0; it < iters; ++it, n += stride) {
    if (n < NNODE) {
      int p0 = rowptr2[2 * n], p1 = rowptr2[2 * n + 1];
      partf[n * HH + c] = edge_gather(hbuf, tab, pk, p0, p1, c, sc, sh, lo);
    }
  }
}

// ---------------- layerA pass 1: high-src edges + partial + hn + matmul + BN1 stats
__global__ void __launch_bounds__(256) k_layerA1(const __half* __restrict__ hbuf,
                                                 const int* __restrict__ rowptr2,
                                                 const unsigned int* __restrict__ pk,
                                                 const __half* __restrict__ tab,
                                                 const float* __restrict__ partf,
                                                 const float* __restrict__ statsC,
                                                 const float* __restrict__ bng,
                                                 const float* __restrict__ bnb,
                                                 const float* __restrict__ w1g,
                                                 const float* __restrict__ b1g,
                                                 const float* __restrict__ epsg,
                                                 __half* __restrict__ y1buf,
                                                 float* __restrict__ statsA,
                                                 int l, int relu) {
  __shared__ float w1s[HH * HH2];
  __shared__ float b1s[HH2];
  __shared__ float affs[HH], affsh[HH];
  __shared__ float tb[8][HH + 1];
  __shared__ float ps[HH2], pq[HH2];
  int t = threadIdx.x;
  const float* w1l = w1g + l * HH * HH2;
  for (int j = t; j < HH * HH2; j += 256) w1s[j] = w1l[j];
  if (t < HH2) { b1s[t] = b1g[l * HH2 + t]; ps[t] = 0.f; pq[t] = 0.f; }
  if (t < HH) {
    if (l == 0) { affs[t] = 1.f; affsh[t] = 0.f; }
    else {
      float sum = statsC[(l - 1) * 64 + t], sq = statsC[(l - 1) * 64 + 32 + t];
      float mean = sum / (float)NNODE;
      float var = fmaxf(sq / (float)NNODE - mean * mean, 0.f);
      float s = bng[(l - 1) * HH + t] * rsqrtf(var + BNEPS);
      affs[t] = s; affsh[t] = bnb[(l - 1) * HH + t] - mean * s;
    }
  }
  int g = t >> 5, c = t & 31;
  float epsv = 1.f + epsg[l];
  float lo = relu ? 0.f : -3.4e38f;
  float s0a = 0.f, s0q = 0.f, s1a = 0.f, s1q = 0.f;
  __syncthreads();
  float sc = affs[c], sh = affsh[c];
  int stride = gridDim.x * 8;
  int iters = (NNODE + stride - 1) / stride;
  int n = blockIdx.x * 8 + g;
  for (int it = 0; it < iters; ++it, n += stride) {
    bool val = n < NNODE;
    float tv = 0.f;
    if (val) {
      int p0 = rowptr2[2 * n + 1], p1 = rowptr2[2 * n + 2];
      float acc = edge_gather(hbuf, tab, pk, p0, p1, c, sc, sh, lo);
      acc += partf[n * HH + c];
      float hn = fmaxf(fmaf(__half2float(hbuf[n * HH + c]), sc, sh), lo);
      tv = fmaf(epsv, hn, acc);
    }
    tb[g][c] = tv;
    __builtin_amdgcn_wave_barrier();
    if (val) {
      float y0 = b1s[c], y1 = b1s[HH + c];
#pragma unroll
      for (int k = 0; k < HH; ++k) {
        float tk = tb[g][k];
        y0 = fmaf(tk, w1s[k * HH2 + c], y0);
        y1 = fmaf(tk, w1s[k * HH2 + HH + c], y1);
      }
      __half hy0 = __float2half(y0), hy1 = __float2half(y1);
      y1buf[n * HH2 + c] = hy0;
      y1buf[n * HH2 + HH + c] = hy1;
      float z0 = __half2float(hy0), z1 = __half2float(hy1);
      s0a += z0; s0q += z0 * z0; s1a += z1; s1q += z1 * z1;
    }
    __builtin_amdgcn_wave_barrier();
  }
  s0a += __shfl_xor(s0a, 32); s0q += __shfl_xor(s0q, 32);
  s1a += __shfl_xor(s1a, 32); s1q += __shfl_xor(s1q, 32);
  if ((t & 32) == 0) {
    atomicAdd(&ps[c], s0a); atomicAdd(&pq[c], s0q);
    atomicAdd(&ps[HH + c], s1a); atomicAdd(&pq[HH + c], s1q);
  }
  __syncthreads();
  if (t < HH2) {
    atomicAdd(&statsA[l * 128 + t], ps[t]);
    atomicAdd(&statsA[l * 128 + 64 + t], pq[t]);
  }
}

// ---------------- layer kernel C: BN1 solve fused; affine->relu->@w2+b2, BN2 stats
__global__ void __launch_bounds__(256) k_layerC(const __half* __restrict__ y1buf,
                                                const float* __restrict__ statsA,
                                                const float* __restrict__ g1,
                                                const float* __restrict__ bb1,
                                                const float* __restrict__ w2g,
                                                const float* __restrict__ b2g,
                                                __half* __restrict__ hbuf,
                                                float* __restrict__ statsC, int l) {
  __shared__ float w2s[HH2 * HH];
  __shared__ float b2s[HH];
  __shared__ float a1s[HH2], a1sh[HH2];
  __shared__ float ab[8][HH2 + 1];
  __shared__ float ps[HH], pq[HH];
  int t = threadIdx.x;
  const float* w2l = w2g + l * HH2 * HH;
  for (int j = t; j < HH2 * HH; j += 256) w2s[j] = w2l[j];
  if (t < HH) { b2s[t] = b2g[l * HH + t]; ps[t] = 0.f; pq[t] = 0.f; }
  if (t < HH2) {
    float sum = statsA[l * 128 + t], sq = statsA[l * 128 + 64 + t];
    float mean = sum / (float)NNODE;
    float var = fmaxf(sq / (float)NNODE - mean * mean, 0.f);
    float s = g1[l * HH2 + t] * rsqrtf(var + BNEPS);
    a1s[t] = s; a1sh[t] = bb1[l * HH2 + t] - mean * s;
  }
  int g = t >> 5, c = t & 31;
  float sa = 0.f, sq = 0.f;
  __syncthreads();
  int stride = gridDim.x * 8;
  int iters = (NNODE + stride - 1) / stride;
  int n = blockIdx.x * 8 + g;
  for (int it = 0; it < iters; ++it, n += stride) {
    bool val = n < NNODE;
    float a0 = 0.f, a1 = 0.f;
    if (val) {
      a0 = fmaf(__half2float(y1buf[n * HH2 + c]), a1s[c], a1sh[c]);
      a1 = fmaf(__half2float(y1buf[n * HH2 + HH + c]), a1s[HH + c], a1sh[HH + c]);
    }
    ab[g][c] = fmaxf(a0, 0.f);
    ab[g][HH + c] = fmaxf(a1, 0.f);
    __builtin_amdgcn_wave_barrier();
    if (val) {
      float z = b2s[c];
#pragma unroll
      for (int k = 0; k < HH2; ++k) z = fmaf(ab[g][k], w2s[k * HH + c], z);
      __half zh = __float2half(z);
      hbuf[n * HH + c] = zh;
      float zq = __half2float(zh);
      sa += zq; sq += zq * zq;
    }
    __builtin_amdgcn_wave_barrier();
  }
  sa += __shfl_xor(sa, 32); sq += __shfl_xor(sq, 32);
  if ((t & 32) == 0) { atomicAdd(&ps[c], sa); atomicAdd(&pq[c], sq); }
  __syncthreads();
  if (t < HH) {
    atomicAdd(&statsC[l * 64 + t], ps[t]);
    atomicAdd(&statsC[l * 64 + 32 + t], pq[t]);
  }
}

// ---------------- output: BN2(last) solve fused + LayerNorm + FULL coalesced write
__global__ void __launch_bounds__(256) k_output(const __half* __restrict__ hbuf,
                                                const float* __restrict__ statsC,
                                                const float* __restrict__ bng,
                                                const float* __restrict__ bnb,
                                                const float* __restrict__ lng,
                                                const float* __restrict__ lnb,
                                                float* __restrict__ out) {
  __shared__ float nrb[16 * 33];
  __shared__ float affs[HH], affsh[HH];
  int t = threadIdx.x;
  if (t < HH) {
    float sum = statsC[(NL - 1) * 64 + t], sq = statsC[(NL - 1) * 64 + 32 + t];
    float mean = sum / (float)NNODE;
    float var = fmaxf(sq / (float)NNODE - mean * mean, 0.f);
    float s = bng[(NL - 1) * HH + t] * rsqrtf(var + BNEPS);
    affs[t] = s; affsh[t] = bnb[(NL - 1) * HH + t] - mean * s;
  }
  __syncthreads();
  int gi = blockIdx.x;
  int g = gi >> 8, i = gi & 255;
  int jlo = (i - KBW > 0) ? i - KBW : 0;
  int jhi = (i + KBW < NNN - 1) ? i + KBW : NNN - 1;
  int cnt = jhi - jlo;
  int Ai = (i <= 8) ? i * (i - 1) / 2 : 28 + 8 * (i - 8);
  int Bi = (i <= 248) ? 8 * i : 2012 - (256 - i) * (255 - i) / 2;
  int nb = g * PGN + Ai + Bi;
  int r = t >> 5, c = t & 31;
  float sc = affs[c], sh = affsh[c];
  float lg = lng[c], lb = lnb[c];
  for (int rr = r; rr < cnt; rr += 8) {
    float v = fmaf(__half2float(hbuf[(nb + rr) * HH + c]), sc, sh);
    float s = v;
#pragma unroll
    for (int off = 16; off > 0; off >>= 1) s += __shfl_xor(s, off, 32);
    float mean = s * (1.f / 32.f);
    float d = v - mean;
    float q = d * d;
#pragma unroll
    for (int off = 16; off > 0; off >>= 1) q += __shfl_xor(q, off, 32);
    float var = q * (1.f / 32.f);
    nrb[rr * 33 + c] = d * rsqrtf(var + BNEPS) * lg + lb;
  }
  __syncthreads();
  int j = t;
  bool valid = (j >= jlo) & (j <= jhi) & (j != i);
  int rr = j - jlo - ((j > i) ? 1 : 0);
  rr = (rr < 0) ? 0 : ((rr > 15) ? 15 : rr);
  size_t ob = (((size_t)g * HH) * NNN + i) * NNN + j;
#pragma unroll
  for (int h = 0; h < HH; ++h) {
    float val = valid ? nrb[rr * 33 + h] : 0.f;
    __builtin_nontemporal_store(val, &out[ob + (size_t)h * NNN * NNN]);
  }
}

extern "C" void kernel_launch(void* const* d_in, const int* in_sizes, int n_in,
                              void* d_out, int out_size, void* d_ws, size_t ws_size,
                              hipStream_t stream) {
  (void)in_sizes; (void)n_in;
  const float* x3d   = (const float*)d_in[0];
  const float* eattr = (const float*)d_in[1];
  const int*   eidx  = (const int*)d_in[2];
  const float* wlen = (const float*)d_in[5];
  const float* blen = (const float*)d_in[6];
  const float* wang = (const float*)d_in[7];
  const float* bang = (const float*)d_in[8];
  const float* w1g  = (const float*)d_in[9];
  const float* b1g  = (const float*)d_in[10];
  const float* g1   = (const float*)d_in[11];
  const float* bb1  = (const float*)d_in[12];
  const float* w2g  = (const float*)d_in[13];
  const float* b2g  = (const float*)d_in[14];
  const float* epsg = (const float*)d_in[15];
  const float* bng  = (const float*)d_in[16];
  const float* bnb  = (const float*)d_in[17];
  const float* lng  = (const float*)d_in[18];
  const float* lnb  = (const float*)d_in[19];
  float* out = (float*)d_out;

  char* ws = (char*)d_ws;
  size_t off = 0;
  auto alloc = [&](size_t bytes) {
    void* p = ws + off;
    off += (bytes + 255) & ~(size_t)255;
    return p;
  };
  unsigned int* pk  = (unsigned int*)alloc((size_t)NEDGE * 4);
  int*   rowptr2    = (int*)alloc((size_t)(N2 + 1) * 4);
  int*   counts     = (int*)alloc((size_t)N2 * 4);
  int*   cursor2    = (int*)alloc((size_t)N2 * 4);
  __half* hbuf      = (__half*)alloc((size_t)NNODE * HH * 2);
  __half* y1buf     = (__half*)alloc((size_t)NNODE * HH2 * 2);
  __half* tab       = (__half*)alloc((size_t)TTAB * HH * 2);
  float* partf      = (float*)alloc((size_t)NNODE * HH * 4);
  float* statsA     = (float*)alloc((NL * 128 + NL * 64) * 4);
  float* statsC     = statsA + NL * 128;
  int*   bsum       = (int*)alloc(1006 * 4);
  int*   boff       = (int*)alloc(1006 * 4);

  if (off > ws_size) {
    hipMemsetAsync(d_out, 0x7F, (size_t)out_size * 4, stream);
    return;
  }

  hipMemsetAsync(counts, 0, (size_t)N2 * 4, stream);
  hipMemsetAsync(statsA, 0, (NL * 128 + NL * 64) * 4, stream);

  k_node_embed<<<NNODE * HH / 256, 256, 0, stream>>>(x3d, wlen, blen, hbuf);
  k_tab<<<TTAB * HH / 256, 256, 0, stream>>>(wang, bang, tab);
  k_hist<<<NEDGE / 256, 256, 0, stream>>>(eidx, eidx + NEDGE, counts);
  k_scan1<<<N2 / 256, 256, 0, stream>>>(counts, bsum);
  k_scan2<<<1, 1024, 0, stream>>>(bsum, boff);
  k_scan3<<<N2 / 256, 256, 0, stream>>>(counts, boff, rowptr2, cursor2);
  k_scatter<<<8048, 256, 0, stream>>>(eidx, eidx + NEDGE, eattr, cursor2, pk);

  for (int l = 0; l < NL; ++l) {
    int relu = l >= 1 ? 1 : 0;
    k_layerA0<<<2048, 256, 0, stream>>>(hbuf, rowptr2, pk, tab, statsC, bng, bnb, partf, l, relu);
    k_layerA1<<<2048, 256, 0, stream>>>(hbuf, rowptr2, pk, tab, partf, statsC, bng, bnb,
                                        w1g, b1g, epsg, y1buf, statsA, l, relu);
    k_layerC<<<2048, 256, 0, stream>>>(y1buf, statsA, g1, bb1, w2g, b2g, hbuf, statsC, l);
  }

  k_output<<<NNN * 32, 256, 0, stream>>>(hbuf, statsC, bng, bnb, lng, lnb, out);
}

// Round 12
// 1081.017 us; speedup vs baseline: 1.2650x; 1.2650x over previous
//
#include <hip/hip_runtime.h>
#include <hip/hip_bf16.h>
#include <hip/hip_fp16.h>

#define HH 32
#define HH2 64
#define NRBF_ 20
#define NL 5
#define NNN 256
#define KBW 8
#define PGN 4024
#define TTAB 4096
constexpr int NNODE = 128768;
constexpr int NEDGE = 2060288;
constexpr float BNEPS = 1e-5f;
constexpr float PI_F = 3.14159265358979323846f;

#define EMB_BLKS (NNODE * HH / 256)      // 16096
#define TAB_BLKS (TTAB * HH / 256)       // 512
#define HIST_BLKS (NEDGE / 256)          // 8048

// ---------------- fused prep: node embed | ea table | dst histogram
__global__ void __launch_bounds__(256) k_prep(const float* __restrict__ x3d,
                                              const float* __restrict__ wlen,
                                              const float* __restrict__ blen,
                                              const float* __restrict__ wang,
                                              const float* __restrict__ bang,
                                              const int* __restrict__ dst,
                                              __half* __restrict__ hbuf,
                                              __half* __restrict__ tab,
                                              int* __restrict__ counts) {
  int b = blockIdx.x;
  int t = threadIdx.x;
  if (b < EMB_BLKS) {
    __shared__ float wl[NRBF_ * HH];
    __shared__ float bl[HH];
    for (int j = t; j < NRBF_ * HH; j += 256) wl[j] = wlen[j];
    if (t < HH) bl[t] = blen[t];
    __syncthreads();
    int idx = b * 256 + t;
    int n = idx >> 5, c = idx & 31;
    float x = x3d[n];
    float acc = bl[c];
#pragma unroll
    for (int k = 0; k < NRBF_; ++k) {
      float d = x - 0.1f * (float)k;
      acc = fmaf(__expf(-10.f * d * d), wl[k * HH + c], acc);
    }
    hbuf[idx] = __float2half(acc);
  } else if (b < EMB_BLKS + TAB_BLKS) {
    __shared__ float wa[NRBF_ * HH];
    __shared__ float ba[HH];
    for (int j = t; j < NRBF_ * HH; j += 256) wa[j] = wang[j];
    if (t < HH) ba[t] = bang[t];
    __syncthreads();
    int idx = (b - EMB_BLKS) * 256 + t;
    int row = idx >> 5, c = idx & 31;
    float ang = (float)row * (PI_F / (float)(TTAB - 1));
    const float step = PI_F / 19.f;
    float acc = ba[c];
#pragma unroll
    for (int k = 0; k < NRBF_; ++k) {
      float d = ang - step * (float)k;
      acc = fmaf(__expf(-10.f * d * d), wa[k * HH + c], acc);
    }
    tab[row * HH + c] = __float2half(acc);
  } else {
    int e = (b - EMB_BLKS - TAB_BLKS) * 256 + t;
    atomicAdd(&counts[dst[e]], 1);
  }
}

// ---------------- scan step 1 (503 blocks x 256)
__global__ void __launch_bounds__(256) k_scan1(const int* __restrict__ counts, int* __restrict__ bsum) {
  __shared__ int sd[256];
  int t = threadIdx.x;
  sd[t] = counts[blockIdx.x * 256 + t];
  __syncthreads();
  for (int s = 128; s > 0; s >>= 1) { if (t < s) sd[t] += sd[t + s]; __syncthreads(); }
  if (t == 0) bsum[blockIdx.x] = sd[0];
}

// ---------------- scan step 2
__global__ void __launch_bounds__(512) k_scan2(const int* __restrict__ bsum, int* __restrict__ boff) {
  __shared__ int sd[512];
  int t = threadIdx.x;
  int v = (t < 503) ? bsum[t] : 0;
  sd[t] = v;
  __syncthreads();
  for (int off = 1; off < 512; off <<= 1) {
    int x = (t >= off) ? sd[t - off] : 0;
    __syncthreads();
    sd[t] += x;
    __syncthreads();
  }
  if (t < 503) boff[t] = sd[t] - v;
}

// ---------------- scan step 3: rowptr + per-node cursor
__global__ void __launch_bounds__(256) k_scan3(const int* __restrict__ counts, const int* __restrict__ boff,
                                               int* __restrict__ rowptr, int* __restrict__ cursor) {
  __shared__ int sd[256];
  int t = threadIdx.x;
  int i = blockIdx.x * 256 + t;
  int v = counts[i];
  sd[t] = v;
  __syncthreads();
  for (int off = 1; off < 256; off <<= 1) {
    int x = (t >= off) ? sd[t - off] : 0;
    __syncthreads();
    sd[t] += x;
    __syncthreads();
  }
  int excl = sd[t] - v + boff[blockIdx.x];
  rowptr[i] = excl;
  cursor[i] = excl;
  if (i == NNODE - 1) rowptr[NNODE] = excl + v;
}

// ---------------- XCD-range-exclusive scatter; packs src(17b) | tab-idx(12b) into 4B
__global__ void __launch_bounds__(256) k_scatter(const int* __restrict__ srcA,
                                                 const int* __restrict__ dstA,
                                                 const float* __restrict__ eattr,
                                                 int* __restrict__ cursor,
                                                 unsigned int* __restrict__ pk) {
  const float angsc = (float)(TTAB - 1) / PI_F;
  int bid = blockIdx.x;
  int x = bid & 7;
  int j = bid >> 3;
  int lo = x * (NNODE / 8);
  int hi = lo + (NNODE / 8);
  int e0 = j * 2048 + threadIdx.x;
#pragma unroll
  for (int k = 0; k < 8; ++k) {
    int e = e0 + k * 256;
    int d = dstA[e];
    if (d >= lo && d < hi) {
      int pos = atomicAdd(&cursor[d], 1);
      unsigned int idx = min((unsigned int)fmaf(eattr[e], angsc, 0.5f), (unsigned int)(TTAB - 1));
      pk[pos] = (unsigned int)srcA[e] | (idx << 17);
    }
  }
}

// ---------------- layerA: 16-lane groups, 2 ch/lane half2 gathers; t@w1+b1; BN1 stats
__global__ void __launch_bounds__(256) k_layerA(const __half* __restrict__ hbuf,
                                                const int* __restrict__ rowptr,
                                                const unsigned int* __restrict__ pk,
                                                const __half* __restrict__ tab,
                                                const float* __restrict__ statsC,
                                                const float* __restrict__ bng,
                                                const float* __restrict__ bnb,
                                                const float* __restrict__ w1g,
                                                const float* __restrict__ b1g,
                                                const float* __restrict__ epsg,
                                                __half* __restrict__ y1buf,
                                                float* __restrict__ statsA,
                                                int l, int relu) {
  __shared__ float w1s[HH * HH2];
  __shared__ float b1s[HH2];
  __shared__ float affs[HH], affsh[HH];
  __shared__ float tb[16][HH + 1];
  __shared__ float ps[HH2], pq[HH2];
  int t = threadIdx.x;
  const float* w1l = w1g + l * HH * HH2;
  for (int j = t; j < HH * HH2; j += 256) w1s[j] = w1l[j];
  if (t < HH2) { b1s[t] = b1g[l * HH2 + t]; ps[t] = 0.f; pq[t] = 0.f; }
  if (t < HH) {
    if (l == 0) { affs[t] = 1.f; affsh[t] = 0.f; }
    else {
      float sum = statsC[(l - 1) * 64 + t], sq = statsC[(l - 1) * 64 + 32 + t];
      float mean = sum / (float)NNODE;
      float var = fmaxf(sq / (float)NNODE - mean * mean, 0.f);
      float s = bng[(l - 1) * HH + t] * rsqrtf(var + BNEPS);
      affs[t] = s; affsh[t] = bnb[(l - 1) * HH + t] - mean * s;
    }
  }
  int g = t >> 4, c = t & 15;
  int c2 = c * 2, c4 = c * 4;
  float epsv = 1.f + epsg[l];
  float lo = relu ? 0.f : -3.4e38f;
  float sA0 = 0.f, sQ0 = 0.f, sA1 = 0.f, sQ1 = 0.f;
  float sA2 = 0.f, sQ2 = 0.f, sA3 = 0.f, sQ3 = 0.f;
  __syncthreads();
  float sc0 = affs[c2], sh0 = affsh[c2];
  float sc1 = affs[c2 + 1], sh1 = affsh[c2 + 1];
  int stride = gridDim.x * 16;
  int iters = (NNODE + stride - 1) / stride;
  int n = blockIdx.x * 16 + g;
  for (int it = 0; it < iters; ++it, n += stride) {
    bool val = n < NNODE;
    if (val) {
      int p0 = rowptr[n], p1 = rowptr[n + 1];
      float2 hn = __half22float2(*(const __half2*)&hbuf[n * HH + c2]);
      float hn0 = fmaxf(fmaf(hn.x, sc0, sh0), lo);
      float hn1 = fmaxf(fmaf(hn.y, sc1, sh1), lo);
      float a0 = 0.f, a1 = 0.f;
      int p = p0;
      for (; p + 8 <= p1; p += 8) {
        unsigned int q0 = __builtin_nontemporal_load(&pk[p]);
        unsigned int q1 = __builtin_nontemporal_load(&pk[p + 1]);
        unsigned int q2 = __builtin_nontemporal_load(&pk[p + 2]);
        unsigned int q3 = __builtin_nontemporal_load(&pk[p + 3]);
        unsigned int q4 = __builtin_nontemporal_load(&pk[p + 4]);
        unsigned int q5 = __builtin_nontemporal_load(&pk[p + 5]);
        unsigned int q6 = __builtin_nontemporal_load(&pk[p + 6]);
        unsigned int q7 = __builtin_nontemporal_load(&pk[p + 7]);
        __half2 H0 = *(const __half2*)&hbuf[(q0 & 0x1FFFF) * HH + c2];
        __half2 H1 = *(const __half2*)&hbuf[(q1 & 0x1FFFF) * HH + c2];
        __half2 H2 = *(const __half2*)&hbuf[(q2 & 0x1FFFF) * HH + c2];
        __half2 H3 = *(const __half2*)&hbuf[(q3 & 0x1FFFF) * HH + c2];
        __half2 H4 = *(const __half2*)&hbuf[(q4 & 0x1FFFF) * HH + c2];
        __half2 H5 = *(const __half2*)&hbuf[(q5 & 0x1FFFF) * HH + c2];
        __half2 H6 = *(const __half2*)&hbuf[(q6 & 0x1FFFF) * HH + c2];
        __half2 H7 = *(const __half2*)&hbuf[(q7 & 0x1FFFF) * HH + c2];
        __half2 E0 = *(const __half2*)&tab[(q0 >> 17) * HH + c2];
        __half2 E1 = *(const __half2*)&tab[(q1 >> 17) * HH + c2];
        __half2 E2 = *(const __half2*)&tab[(q2 >> 17) * HH + c2];
        __half2 E3 = *(const __half2*)&tab[(q3 >> 17) * HH + c2];
        __half2 E4 = *(const __half2*)&tab[(q4 >> 17) * HH + c2];
        __half2 E5 = *(const __half2*)&tab[(q5 >> 17) * HH + c2];
        __half2 E6 = *(const __half2*)&tab[(q6 >> 17) * HH + c2];
        __half2 E7 = *(const __half2*)&tab[(q7 >> 17) * HH + c2];
        float2 f, e;
        f = __half22float2(H0); e = __half22float2(E0);
        a0 += fmaxf(fmaxf(fmaf(f.x, sc0, sh0), lo) + e.x, 0.f);
        a1 += fmaxf(fmaxf(fmaf(f.y, sc1, sh1), lo) + e.y, 0.f);
        f = __half22float2(H1); e = __half22float2(E1);
        a0 += fmaxf(fmaxf(fmaf(f.x, sc0, sh0), lo) + e.x, 0.f);
        a1 += fmaxf(fmaxf(fmaf(f.y, sc1, sh1), lo) + e.y, 0.f);
        f = __half22float2(H2); e = __half22float2(E2);
        a0 += fmaxf(fmaxf(fmaf(f.x, sc0, sh0), lo) + e.x, 0.f);
        a1 += fmaxf(fmaxf(fmaf(f.y, sc1, sh1), lo) + e.y, 0.f);
        f = __half22float2(H3); e = __half22float2(E3);
        a0 += fmaxf(fmaxf(fmaf(f.x, sc0, sh0), lo) + e.x, 0.f);
        a1 += fmaxf(fmaxf(fmaf(f.y, sc1, sh1), lo) + e.y, 0.f);
        f = __half22float2(H4); e = __half22float2(E4);
        a0 += fmaxf(fmaxf(fmaf(f.x, sc0, sh0), lo) + e.x, 0.f);
        a1 += fmaxf(fmaxf(fmaf(f.y, sc1, sh1), lo) + e.y, 0.f);
        f = __half22float2(H5); e = __half22float2(E5);
        a0 += fmaxf(fmaxf(fmaf(f.x, sc0, sh0), lo) + e.x, 0.f);
        a1 += fmaxf(fmaxf(fmaf(f.y, sc1, sh1), lo) + e.y, 0.f);
        f = __half22float2(H6); e = __half22float2(E6);
        a0 += fmaxf(fmaxf(fmaf(f.x, sc0, sh0), lo) + e.x, 0.f);
        a1 += fmaxf(fmaxf(fmaf(f.y, sc1, sh1), lo) + e.y, 0.f);
        f = __half22float2(H7); e = __half22float2(E7);
        a0 += fmaxf(fmaxf(fmaf(f.x, sc0, sh0), lo) + e.x, 0.f);
        a1 += fmaxf(fmaxf(fmaf(f.y, sc1, sh1), lo) + e.y, 0.f);
      }
      for (; p < p1; ++p) {
        unsigned int q0 = __builtin_nontemporal_load(&pk[p]);
        float2 f = __half22float2(*(const __half2*)&hbuf[(q0 & 0x1FFFF) * HH + c2]);
        float2 e = __half22float2(*(const __half2*)&tab[(q0 >> 17) * HH + c2]);
        a0 += fmaxf(fmaxf(fmaf(f.x, sc0, sh0), lo) + e.x, 0.f);
        a1 += fmaxf(fmaxf(fmaf(f.y, sc1, sh1), lo) + e.y, 0.f);
      }
      tb[g][c2] = fmaf(epsv, hn0, a0);
      tb[g][c2 + 1] = fmaf(epsv, hn1, a1);
    }
    __builtin_amdgcn_wave_barrier();
    if (val) {
      float y0 = b1s[c4], y1 = b1s[c4 + 1], y2 = b1s[c4 + 2], y3 = b1s[c4 + 3];
#pragma unroll
      for (int k = 0; k < HH; ++k) {
        float tk = tb[g][k];
        y0 = fmaf(tk, w1s[k * HH2 + c4], y0);
        y1 = fmaf(tk, w1s[k * HH2 + c4 + 1], y1);
        y2 = fmaf(tk, w1s[k * HH2 + c4 + 2], y2);
        y3 = fmaf(tk, w1s[k * HH2 + c4 + 3], y3);
      }
      __half2 h01 = __floats2half2_rn(y0, y1);
      __half2 h23 = __floats2half2_rn(y2, y3);
      *(__half2*)&y1buf[n * HH2 + c4] = h01;
      *(__half2*)&y1buf[n * HH2 + c4 + 2] = h23;
      float2 z01 = __half22float2(h01), z23 = __half22float2(h23);
      sA0 += z01.x; sQ0 += z01.x * z01.x;
      sA1 += z01.y; sQ1 += z01.y * z01.y;
      sA2 += z23.x; sQ2 += z23.x * z23.x;
      sA3 += z23.y; sQ3 += z23.y * z23.y;
    }
    __builtin_amdgcn_wave_barrier();
  }
  sA0 += __shfl_xor(sA0, 16); sA0 += __shfl_xor(sA0, 32);
  sQ0 += __shfl_xor(sQ0, 16); sQ0 += __shfl_xor(sQ0, 32);
  sA1 += __shfl_xor(sA1, 16); sA1 += __shfl_xor(sA1, 32);
  sQ1 += __shfl_xor(sQ1, 16); sQ1 += __shfl_xor(sQ1, 32);
  sA2 += __shfl_xor(sA2, 16); sA2 += __shfl_xor(sA2, 32);
  sQ2 += __shfl_xor(sQ2, 16); sQ2 += __shfl_xor(sQ2, 32);
  sA3 += __shfl_xor(sA3, 16); sA3 += __shfl_xor(sA3, 32);
  sQ3 += __shfl_xor(sQ3, 16); sQ3 += __shfl_xor(sQ3, 32);
  if ((t & 63) < 16) {
    atomicAdd(&ps[c4], sA0); atomicAdd(&pq[c4], sQ0);
    atomicAdd(&ps[c4 + 1], sA1); atomicAdd(&pq[c4 + 1], sQ1);
    atomicAdd(&ps[c4 + 2], sA2); atomicAdd(&pq[c4 + 2], sQ2);
    atomicAdd(&ps[c4 + 3], sA3); atomicAdd(&pq[c4 + 3], sQ3);
  }
  __syncthreads();
  if (t < HH2) {
    atomicAdd(&statsA[l * 128 + t], ps[t]);
    atomicAdd(&statsA[l * 128 + 64 + t], pq[t]);
  }
}

// ---------------- layerC: 16-lane groups; BN1 solve fused; affine->relu->@w2+b2; BN2 stats
__global__ void __launch_bounds__(256) k_layerC(const __half* __restrict__ y1buf,
                                                const float* __restrict__ statsA,
                                                const float* __restrict__ g1,
                                                const float* __restrict__ bb1,
                                                const float* __restrict__ w2g,
                                                const float* __restrict__ b2g,
                                                __half* __restrict__ hbuf,
                                                float* __restrict__ statsC, int l) {
  __shared__ float w2s[HH2 * HH];
  __shared__ float b2s[HH];
  __shared__ float a1s[HH2], a1sh[HH2];
  __shared__ float ab[16][HH2 + 2];
  __shared__ float ps[HH], pq[HH];
  int t = threadIdx.x;
  const float* w2l = w2g + l * HH2 * HH;
  for (int j = t; j < HH2 * HH; j += 256) w2s[j] = w2l[j];
  if (t < HH) { b2s[t] = b2g[l * HH + t]; ps[t] = 0.f; pq[t] = 0.f; }
  if (t < HH2) {
    float sum = statsA[l * 128 + t], sq = statsA[l * 128 + 64 + t];
    float mean = sum / (float)NNODE;
    float var = fmaxf(sq / (float)NNODE - mean * mean, 0.f);
    float s = g1[l * HH2 + t] * rsqrtf(var + BNEPS);
    a1s[t] = s; a1sh[t] = bb1[l * HH2 + t] - mean * s;
  }
  int g = t >> 4, c = t & 15;
  int c2 = c * 2;
  float sa0 = 0.f, sq0 = 0.f, sa1 = 0.f, sq1 = 0.f;
  __syncthreads();
  int stride = gridDim.x * 16;
  int iters = (NNODE + stride - 1) / stride;
  int n = blockIdx.x * 16 + g;
  for (int it = 0; it < iters; ++it, n += stride) {
    bool val = n < NNODE;
    if (val) {
      float2 ylo = __half22float2(*(const __half2*)&y1buf[n * HH2 + c2]);
      float2 yhi = __half22float2(*(const __half2*)&y1buf[n * HH2 + 32 + c2]);
      ab[g][c2] = fmaxf(fmaf(ylo.x, a1s[c2], a1sh[c2]), 0.f);
      ab[g][c2 + 1] = fmaxf(fmaf(ylo.y, a1s[c2 + 1], a1sh[c2 + 1]), 0.f);
      ab[g][32 + c2] = fmaxf(fmaf(yhi.x, a1s[32 + c2], a1sh[32 + c2]), 0.f);
      ab[g][32 + c2 + 1] = fmaxf(fmaf(yhi.y, a1s[32 + c2 + 1], a1sh[32 + c2 + 1]), 0.f);
    }
    __builtin_amdgcn_wave_barrier();
    if (val) {
      float z0 = b2s[c2], z1 = b2s[c2 + 1];
#pragma unroll
      for (int k = 0; k < HH2; ++k) {
        float ak = ab[g][k];
        z0 = fmaf(ak, w2s[k * HH + c2], z0);
        z1 = fmaf(ak, w2s[k * HH + c2 + 1], z1);
      }
      __half2 zh = __floats2half2_rn(z0, z1);
      *(__half2*)&hbuf[n * HH + c2] = zh;
      float2 zf = __half22float2(zh);
      sa0 += zf.x; sq0 += zf.x * zf.x;
      sa1 += zf.y; sq1 += zf.y * zf.y;
    }
    __builtin_amdgcn_wave_barrier();
  }
  sa0 += __shfl_xor(sa0, 16); sa0 += __shfl_xor(sa0, 32);
  sq0 += __shfl_xor(sq0, 16); sq0 += __shfl_xor(sq0, 32);
  sa1 += __shfl_xor(sa1, 16); sa1 += __shfl_xor(sa1, 32);
  sq1 += __shfl_xor(sq1, 16); sq1 += __shfl_xor(sq1, 32);
  if ((t & 63) < 16) {
    atomicAdd(&ps[c2], sa0); atomicAdd(&pq[c2], sq0);
    atomicAdd(&ps[c2 + 1], sa1); atomicAdd(&pq[c2 + 1], sq1);
  }
  __syncthreads();
  if (t < HH) atomicAdd(&statsC[l * 64 + t], ps[t]);
  else if (t < HH2) atomicAdd(&statsC[l * 64 + t], pq[t - HH]);
}

// ---------------- output: BN2(last) solve fused + LayerNorm + FULL coalesced write
__global__ void __launch_bounds__(256) k_output(const __half* __restrict__ hbuf,
                                                const float* __restrict__ statsC,
                                                const float* __restrict__ bng,
                                                const float* __restrict__ bnb,
                                                const float* __restrict__ lng,
                                                const float* __restrict__ lnb,
                                                float* __restrict__ out) {
  __shared__ float nrb[16 * 33];
  __shared__ float affs[HH], affsh[HH];
  int t = threadIdx.x;
  if (t < HH) {
    float sum = statsC[(NL - 1) * 64 + t], sq = statsC[(NL - 1) * 64 + 32 + t];
    float mean = sum / (float)NNODE;
    float var = fmaxf(sq / (float)NNODE - mean * mean, 0.f);
    float s = bng[(NL - 1) * HH + t] * rsqrtf(var + BNEPS);
    affs[t] = s; affsh[t] = bnb[(NL - 1) * HH + t] - mean * s;
  }
  __syncthreads();
  int gi = blockIdx.x;
  int g = gi >> 8, i = gi & 255;
  int jlo = (i - KBW > 0) ? i - KBW : 0;
  int jhi = (i + KBW < NNN - 1) ? i + KBW : NNN - 1;
  int cnt = jhi - jlo;
  int Ai = (i <= 8) ? i * (i - 1) / 2 : 28 + 8 * (i - 8);
  int Bi = (i <= 248) ? 8 * i : 2012 - (256 - i) * (255 - i) / 2;
  int nb = g * PGN + Ai + Bi;
  int r = t >> 5, c = t & 31;
  float sc = affs[c], sh = affsh[c];
  float lg = lng[c], lb = lnb[c];
  for (int rr = r; rr < cnt; rr += 8) {
    float v = fmaf(__half2float(hbuf[(nb + rr) * HH + c]), sc, sh);
    float s = v;
#pragma unroll
    for (int off = 16; off > 0; off >>= 1) s += __shfl_xor(s, off, 32);
    float mean = s * (1.f / 32.f);
    float d = v - mean;
    float q = d * d;
#pragma unroll
    for (int off = 16; off > 0; off >>= 1) q += __shfl_xor(q, off, 32);
    float var = q * (1.f / 32.f);
    nrb[rr * 33 + c] = d * rsqrtf(var + BNEPS) * lg + lb;
  }
  __syncthreads();
  int j = t;
  bool valid = (j >= jlo) & (j <= jhi) & (j != i);
  int rr = j - jlo - ((j > i) ? 1 : 0);
  rr = (rr < 0) ? 0 : ((rr > 15) ? 15 : rr);
  size_t ob = (((size_t)g * HH) * NNN + i) * NNN + j;
#pragma unroll
  for (int h = 0; h < HH; ++h) {
    float val = valid ? nrb[rr * 33 + h] : 0.f;
    __builtin_nontemporal_store(val, &out[ob + (size_t)h * NNN * NNN]);
  }
}

extern "C" void kernel_launch(void* const* d_in, const int* in_sizes, int n_in,
                              void* d_out, int out_size, void* d_ws, size_t ws_size,
                              hipStream_t stream) {
  (void)in_sizes; (void)n_in;
  const float* x3d   = (const float*)d_in[0];
  const float* eattr = (const float*)d_in[1];
  const int*   eidx  = (const int*)d_in[2];
  const float* wlen = (const float*)d_in[5];
  const float* blen = (const float*)d_in[6];
  const float* wang = (const float*)d_in[7];
  const float* bang = (const float*)d_in[8];
  const float* w1g  = (const float*)d_in[9];
  const float* b1g  = (const float*)d_in[10];
  const float* g1   = (const float*)d_in[11];
  const float* bb1  = (const float*)d_in[12];
  const float* w2g  = (const float*)d_in[13];
  const float* b2g  = (const float*)d_in[14];
  const float* epsg = (const float*)d_in[15];
  const float* bng  = (const float*)d_in[16];
  const float* bnb  = (const float*)d_in[17];
  const float* lng  = (const float*)d_in[18];
  const float* lnb  = (const float*)d_in[19];
  float* out = (float*)d_out;

  char* ws = (char*)d_ws;
  size_t off = 0;
  auto alloc = [&](size_t bytes) {
    void* p = ws + off;
    off += (bytes + 255) & ~(size_t)255;
    return p;
  };
  unsigned int* pk  = (unsigned int*)alloc((size_t)NEDGE * 4);
  int*   rowptr     = (int*)alloc((size_t)(NNODE + 1) * 4);
  // counts and stats contiguous (NNODE*4 is 256-aligned) -> single memset
  int*   counts     = (int*)alloc((size_t)NNODE * 4);
  float* statsA     = (float*)alloc((NL * 128 + NL * 64) * 4);
  float* statsC     = statsA + NL * 128;
  int*   cursor     = (int*)alloc((size_t)NNODE * 4);
  __half* hbuf      = (__half*)alloc((size_t)NNODE * HH * 2);
  __half* y1buf     = (__half*)alloc((size_t)NNODE * HH2 * 2);
  __half* tab       = (__half*)alloc((size_t)TTAB * HH * 2);
  int*   bsum       = (int*)alloc(503 * 4);
  int*   boff       = (int*)alloc(503 * 4);

  if (off > ws_size) {
    hipMemsetAsync(d_out, 0x7F, (size_t)out_size * 4, stream);
    return;
  }

  hipMemsetAsync(counts, 0, (size_t)NNODE * 4 + (NL * 128 + NL * 64) * 4, stream);

  k_prep<<<EMB_BLKS + TAB_BLKS + HIST_BLKS, 256, 0, stream>>>(x3d, wlen, blen, wang, bang,
                                                              eidx + NEDGE, hbuf, tab, counts);
  k_scan1<<<NNODE / 256, 256, 0, stream>>>(counts, bsum);
  k_scan2<<<1, 512, 0, stream>>>(bsum, boff);
  k_scan3<<<NNODE / 256, 256, 0, stream>>>(counts, boff, rowptr, cursor);
  k_scatter<<<8048, 256, 0, stream>>>(eidx, eidx + NEDGE, eattr, cursor, pk);

  for (int l = 0; l < NL; ++l) {
    int relu = l >= 1 ? 1 : 0;
    k_layerA<<<2048, 256, 0, stream>>>(hbuf, rowptr, pk, tab, statsC, bng, bnb,
                                       w1g, b1g, epsg, y1buf, statsA, l, relu);
    k_layerC<<<2048, 256, 0, stream>>>(y1buf, statsA, g1, bb1, w2g, b2g, hbuf, statsC, l);
  }

  k_output<<<NNN * 32, 256, 0, stream>>>(hbuf, statsC, bng, bnb, lng, lnb, out);
}

// Round 13
// 945.697 us; speedup vs baseline: 1.4460x; 1.1431x over previous
//
#include <hip/hip_runtime.h>
#include <hip/hip_bf16.h>
#include <hip/hip_fp16.h>

#define HH 32
#define HH2 64
#define NRBF_ 20
#define NL 5
#define NNN 256
#define KBW 8
#define PGN 4024
#define TTAB 4096
constexpr int NNODE = 128768;
constexpr int NEDGE = 2060288;
constexpr float BNEPS = 1e-5f;
constexpr float PI_F = 3.14159265358979323846f;

#define EMB_BLKS (NNODE * HH / 256)      // 16096
#define TAB_BLKS (TTAB * HH / 256)       // 512
#define HIST_BLKS (NEDGE / 256)          // 8048

// ---------------- fused prep: node embed | ea table | dst histogram
__global__ void __launch_bounds__(256) k_prep(const float* __restrict__ x3d,
                                              const float* __restrict__ wlen,
                                              const float* __restrict__ blen,
                                              const float* __restrict__ wang,
                                              const float* __restrict__ bang,
                                              const int* __restrict__ dst,
                                              __half* __restrict__ hbuf,
                                              __half* __restrict__ tab,
                                              int* __restrict__ counts) {
  int b = blockIdx.x;
  int t = threadIdx.x;
  if (b < EMB_BLKS) {
    __shared__ float wl[NRBF_ * HH];
    __shared__ float bl[HH];
    for (int j = t; j < NRBF_ * HH; j += 256) wl[j] = wlen[j];
    if (t < HH) bl[t] = blen[t];
    __syncthreads();
    int idx = b * 256 + t;
    int n = idx >> 5, c = idx & 31;
    float x = x3d[n];
    float acc = bl[c];
#pragma unroll
    for (int k = 0; k < NRBF_; ++k) {
      float d = x - 0.1f * (float)k;
      acc = fmaf(__expf(-10.f * d * d), wl[k * HH + c], acc);
    }
    hbuf[idx] = __float2half(acc);
  } else if (b < EMB_BLKS + TAB_BLKS) {
    __shared__ float wa[NRBF_ * HH];
    __shared__ float ba[HH];
    for (int j = t; j < NRBF_ * HH; j += 256) wa[j] = wang[j];
    if (t < HH) ba[t] = bang[t];
    __syncthreads();
    int idx = (b - EMB_BLKS) * 256 + t;
    int row = idx >> 5, c = idx & 31;
    float ang = (float)row * (PI_F / (float)(TTAB - 1));
    const float step = PI_F / 19.f;
    float acc = ba[c];
#pragma unroll
    for (int k = 0; k < NRBF_; ++k) {
      float d = ang - step * (float)k;
      acc = fmaf(__expf(-10.f * d * d), wa[k * HH + c], acc);
    }
    tab[row * HH + c] = __float2half(acc);
  } else {
    int e = (b - EMB_BLKS - TAB_BLKS) * 256 + t;
    atomicAdd(&counts[dst[e]], 1);
  }
}

// ---------------- scan step 1 (503 blocks x 256)
__global__ void __launch_bounds__(256) k_scan1(const int* __restrict__ counts, int* __restrict__ bsum) {
  __shared__ int sd[256];
  int t = threadIdx.x;
  sd[t] = counts[blockIdx.x * 256 + t];
  __syncthreads();
  for (int s = 128; s > 0; s >>= 1) { if (t < s) sd[t] += sd[t + s]; __syncthreads(); }
  if (t == 0) bsum[blockIdx.x] = sd[0];
}

// ---------------- scan step 2
__global__ void __launch_bounds__(512) k_scan2(const int* __restrict__ bsum, int* __restrict__ boff) {
  __shared__ int sd[512];
  int t = threadIdx.x;
  int v = (t < 503) ? bsum[t] : 0;
  sd[t] = v;
  __syncthreads();
  for (int off = 1; off < 512; off <<= 1) {
    int x = (t >= off) ? sd[t - off] : 0;
    __syncthreads();
    sd[t] += x;
    __syncthreads();
  }
  if (t < 503) boff[t] = sd[t] - v;
}

// ---------------- scan step 3: rowptr + per-node cursor
__global__ void __launch_bounds__(256) k_scan3(const int* __restrict__ counts, const int* __restrict__ boff,
                                               int* __restrict__ rowptr, int* __restrict__ cursor) {
  __shared__ int sd[256];
  int t = threadIdx.x;
  int i = blockIdx.x * 256 + t;
  int v = counts[i];
  sd[t] = v;
  __syncthreads();
  for (int off = 1; off < 256; off <<= 1) {
    int x = (t >= off) ? sd[t - off] : 0;
    __syncthreads();
    sd[t] += x;
    __syncthreads();
  }
  int excl = sd[t] - v + boff[blockIdx.x];
  rowptr[i] = excl;
  cursor[i] = excl;
  if (i == NNODE - 1) rowptr[NNODE] = excl + v;
}

// ---------------- XCD-range-exclusive scatter; packs src(17b) | tab-idx(12b) into 4B
__global__ void __launch_bounds__(256) k_scatter(const int* __restrict__ srcA,
                                                 const int* __restrict__ dstA,
                                                 const float* __restrict__ eattr,
                                                 int* __restrict__ cursor,
                                                 unsigned int* __restrict__ pk) {
  const float angsc = (float)(TTAB - 1) / PI_F;
  int bid = blockIdx.x;
  int x = bid & 7;
  int j = bid >> 3;
  int lo = x * (NNODE / 8);
  int hi = lo + (NNODE / 8);
  int e0 = j * 2048 + threadIdx.x;
#pragma unroll
  for (int k = 0; k < 8; ++k) {
    int e = e0 + k * 256;
    int d = dstA[e];
    if (d >= lo && d < hi) {
      int pos = atomicAdd(&cursor[d], 1);
      unsigned int idx = min((unsigned int)fmaf(eattr[e], angsc, 0.5f), (unsigned int)(TTAB - 1));
      pk[pos] = (unsigned int)srcA[e] | (idx << 17);
    }
  }
}

// ---------------- layerA: 8-lane groups, 4 ch/lane, masked full-width batches
__global__ void __launch_bounds__(256) k_layerA(const __half* __restrict__ hbuf,
                                                const int* __restrict__ rowptr,
                                                const unsigned int* __restrict__ pk,
                                                const __half* __restrict__ tab,
                                                const float* __restrict__ statsC,
                                                const float* __restrict__ bng,
                                                const float* __restrict__ bnb,
                                                const float* __restrict__ w1g,
                                                const float* __restrict__ b1g,
                                                const float* __restrict__ epsg,
                                                __half* __restrict__ y1buf,
                                                float* __restrict__ statsA,
                                                int l, int relu) {
  __shared__ float w1s[HH * HH2];
  __shared__ float b1s[HH2];
  __shared__ float affs[HH], affsh[HH];
  __shared__ float tb[32][HH + 1];
  __shared__ float ps[HH2], pq[HH2];
  int t = threadIdx.x;
  const float* w1l = w1g + l * HH * HH2;
  for (int j = t; j < HH * HH2; j += 256) w1s[j] = w1l[j];
  if (t < HH2) { b1s[t] = b1g[l * HH2 + t]; ps[t] = 0.f; pq[t] = 0.f; }
  if (t < HH) {
    if (l == 0) { affs[t] = 1.f; affsh[t] = 0.f; }
    else {
      float sum = statsC[(l - 1) * 64 + t], sq = statsC[(l - 1) * 64 + 32 + t];
      float mean = sum / (float)NNODE;
      float var = fmaxf(sq / (float)NNODE - mean * mean, 0.f);
      float s = bng[(l - 1) * HH + t] * rsqrtf(var + BNEPS);
      affs[t] = s; affsh[t] = bnb[(l - 1) * HH + t] - mean * s;
    }
  }
  int g = t >> 3, c = t & 7;
  int c4 = c * 4, c8 = c * 8;
  float epsv = 1.f + epsg[l];
  float lo = relu ? 0.f : -3.4e38f;
  float sA0 = 0.f, sA1 = 0.f, sA2 = 0.f, sA3 = 0.f, sA4 = 0.f, sA5 = 0.f, sA6 = 0.f, sA7 = 0.f;
  float sQ0 = 0.f, sQ1 = 0.f, sQ2 = 0.f, sQ3 = 0.f, sQ4 = 0.f, sQ5 = 0.f, sQ6 = 0.f, sQ7 = 0.f;
  __syncthreads();
  float sc0 = affs[c4], sh0 = affsh[c4];
  float sc1 = affs[c4 + 1], sh1 = affsh[c4 + 1];
  float sc2 = affs[c4 + 2], sh2 = affsh[c4 + 2];
  float sc3 = affs[c4 + 3], sh3 = affsh[c4 + 3];
  int stride = gridDim.x * 32;
  int iters = (NNODE + stride - 1) / stride;
  int n = blockIdx.x * 32 + g;
  for (int it = 0; it < iters; ++it, n += stride) {
    bool val = n < NNODE;
    if (val) {
      int p0 = rowptr[n], p1 = rowptr[n + 1];
      uint2 HN = *(const uint2*)&hbuf[n * HH + c4];
      float2 hn01 = __half22float2(*(__half2*)&HN.x);
      float2 hn23 = __half22float2(*(__half2*)&HN.y);
      float a0 = 0.f, a1 = 0.f, a2 = 0.f, a3 = 0.f;
      for (int p = p0; p < p1; p += 8) {
        unsigned int qv[8];
        float okf[8];
        uint2 Hv[8], Ev[8];
#pragma unroll
        for (int i = 0; i < 8; ++i) {
          int pi = p + i;
          bool ok = pi < p1;
          okf[i] = ok ? 1.f : 0.f;
          qv[i] = __builtin_nontemporal_load(&pk[ok ? pi : p0]);
        }
#pragma unroll
        for (int i = 0; i < 8; ++i) {
          Hv[i] = *(const uint2*)&hbuf[(qv[i] & 0x1FFFF) * HH + c4];
          Ev[i] = *(const uint2*)&tab[(qv[i] >> 17) * HH + c4];
        }
#pragma unroll
        for (int i = 0; i < 8; ++i) {
          float2 f01 = __half22float2(*(__half2*)&Hv[i].x);
          float2 f23 = __half22float2(*(__half2*)&Hv[i].y);
          float2 e01 = __half22float2(*(__half2*)&Ev[i].x);
          float2 e23 = __half22float2(*(__half2*)&Ev[i].y);
          a0 += okf[i] * fmaxf(fmaxf(fmaf(f01.x, sc0, sh0), lo) + e01.x, 0.f);
          a1 += okf[i] * fmaxf(fmaxf(fmaf(f01.y, sc1, sh1), lo) + e01.y, 0.f);
          a2 += okf[i] * fmaxf(fmaxf(fmaf(f23.x, sc2, sh2), lo) + e23.x, 0.f);
          a3 += okf[i] * fmaxf(fmaxf(fmaf(f23.y, sc3, sh3), lo) + e23.y, 0.f);
        }
      }
      tb[g][c4]     = fmaf(epsv, fmaxf(fmaf(hn01.x, sc0, sh0), lo), a0);
      tb[g][c4 + 1] = fmaf(epsv, fmaxf(fmaf(hn01.y, sc1, sh1), lo), a1);
      tb[g][c4 + 2] = fmaf(epsv, fmaxf(fmaf(hn23.x, sc2, sh2), lo), a2);
      tb[g][c4 + 3] = fmaf(epsv, fmaxf(fmaf(hn23.y, sc3, sh3), lo), a3);
    }
    __builtin_amdgcn_wave_barrier();
    if (val) {
      float y0 = b1s[c8], y1 = b1s[c8 + 1], y2 = b1s[c8 + 2], y3 = b1s[c8 + 3];
      float y4 = b1s[c8 + 4], y5 = b1s[c8 + 5], y6 = b1s[c8 + 6], y7 = b1s[c8 + 7];
#pragma unroll
      for (int k = 0; k < HH; ++k) {
        float tk = tb[g][k];
        const float* wr = &w1s[k * HH2 + c8];
        y0 = fmaf(tk, wr[0], y0); y1 = fmaf(tk, wr[1], y1);
        y2 = fmaf(tk, wr[2], y2); y3 = fmaf(tk, wr[3], y3);
        y4 = fmaf(tk, wr[4], y4); y5 = fmaf(tk, wr[5], y5);
        y6 = fmaf(tk, wr[6], y6); y7 = fmaf(tk, wr[7], y7);
      }
      __half2 h01 = __floats2half2_rn(y0, y1);
      __half2 h23 = __floats2half2_rn(y2, y3);
      __half2 h45 = __floats2half2_rn(y4, y5);
      __half2 h67 = __floats2half2_rn(y6, y7);
      uint4 pack;
      pack.x = *(unsigned int*)&h01; pack.y = *(unsigned int*)&h23;
      pack.z = *(unsigned int*)&h45; pack.w = *(unsigned int*)&h67;
      *(uint4*)&y1buf[n * HH2 + c8] = pack;
      float2 z01 = __half22float2(h01), z23 = __half22float2(h23);
      float2 z45 = __half22float2(h45), z67 = __half22float2(h67);
      sA0 += z01.x; sQ0 += z01.x * z01.x; sA1 += z01.y; sQ1 += z01.y * z01.y;
      sA2 += z23.x; sQ2 += z23.x * z23.x; sA3 += z23.y; sQ3 += z23.y * z23.y;
      sA4 += z45.x; sQ4 += z45.x * z45.x; sA5 += z45.y; sQ5 += z45.y * z45.y;
      sA6 += z67.x; sQ6 += z67.x * z67.x; sA7 += z67.y; sQ7 += z67.y * z67.y;
    }
    __builtin_amdgcn_wave_barrier();
  }
  // reduce over lanes sharing c (xor bits 3,4,5 of lane id)
#define RED(v) v += __shfl_xor(v, 8); v += __shfl_xor(v, 16); v += __shfl_xor(v, 32);
  RED(sA0) RED(sA1) RED(sA2) RED(sA3) RED(sA4) RED(sA5) RED(sA6) RED(sA7)
  RED(sQ0) RED(sQ1) RED(sQ2) RED(sQ3) RED(sQ4) RED(sQ5) RED(sQ6) RED(sQ7)
#undef RED
  if ((t & 63) < 8) {
    atomicAdd(&ps[c8], sA0); atomicAdd(&ps[c8 + 1], sA1);
    atomicAdd(&ps[c8 + 2], sA2); atomicAdd(&ps[c8 + 3], sA3);
    atomicAdd(&ps[c8 + 4], sA4); atomicAdd(&ps[c8 + 5], sA5);
    atomicAdd(&ps[c8 + 6], sA6); atomicAdd(&ps[c8 + 7], sA7);
    atomicAdd(&pq[c8], sQ0); atomicAdd(&pq[c8 + 1], sQ1);
    atomicAdd(&pq[c8 + 2], sQ2); atomicAdd(&pq[c8 + 3], sQ3);
    atomicAdd(&pq[c8 + 4], sQ4); atomicAdd(&pq[c8 + 5], sQ5);
    atomicAdd(&pq[c8 + 6], sQ6); atomicAdd(&pq[c8 + 7], sQ7);
  }
  __syncthreads();
  if (t < HH2) {
    atomicAdd(&statsA[l * 128 + t], ps[t]);
    atomicAdd(&statsA[l * 128 + 64 + t], pq[t]);
  }
}

// ---------------- layerC: 8-lane groups; BN1 solve fused; affine->relu->@w2+b2; BN2 stats
__global__ void __launch_bounds__(256) k_layerC(const __half* __restrict__ y1buf,
                                                const float* __restrict__ statsA,
                                                const float* __restrict__ g1,
                                                const float* __restrict__ bb1,
                                                const float* __restrict__ w2g,
                                                const float* __restrict__ b2g,
                                                __half* __restrict__ hbuf,
                                                float* __restrict__ statsC, int l) {
  __shared__ float w2s[HH2 * HH];
  __shared__ float b2s[HH];
  __shared__ float a1s[HH2], a1sh[HH2];
  __shared__ float ab[32][HH2 + 2];
  __shared__ float ps[HH], pq[HH];
  int t = threadIdx.x;
  const float* w2l = w2g + l * HH2 * HH;
  for (int j = t; j < HH2 * HH; j += 256) w2s[j] = w2l[j];
  if (t < HH) { b2s[t] = b2g[l * HH + t]; ps[t] = 0.f; pq[t] = 0.f; }
  if (t < HH2) {
    float sum = statsA[l * 128 + t], sq = statsA[l * 128 + 64 + t];
    float mean = sum / (float)NNODE;
    float var = fmaxf(sq / (float)NNODE - mean * mean, 0.f);
    float s = g1[l * HH2 + t] * rsqrtf(var + BNEPS);
    a1s[t] = s; a1sh[t] = bb1[l * HH2 + t] - mean * s;
  }
  int g = t >> 3, c = t & 7;
  int c8 = c * 8, c4 = c * 4;
  float sa0 = 0.f, sq0 = 0.f, sa1 = 0.f, sq1 = 0.f;
  float sa2 = 0.f, sq2 = 0.f, sa3 = 0.f, sq3 = 0.f;
  __syncthreads();
  int stride = gridDim.x * 32;
  int iters = (NNODE + stride - 1) / stride;
  int n = blockIdx.x * 32 + g;
  for (int it = 0; it < iters; ++it, n += stride) {
    bool val = n < NNODE;
    if (val) {
      uint4 Y = *(const uint4*)&y1buf[n * HH2 + c8];
      float2 y01 = __half22float2(*(__half2*)&Y.x);
      float2 y23 = __half22float2(*(__half2*)&Y.y);
      float2 y45 = __half22float2(*(__half2*)&Y.z);
      float2 y67 = __half22float2(*(__half2*)&Y.w);
      ab[g][c8]     = fmaxf(fmaf(y01.x, a1s[c8],     a1sh[c8]),     0.f);
      ab[g][c8 + 1] = fmaxf(fmaf(y01.y, a1s[c8 + 1], a1sh[c8 + 1]), 0.f);
      ab[g][c8 + 2] = fmaxf(fmaf(y23.x, a1s[c8 + 2], a1sh[c8 + 2]), 0.f);
      ab[g][c8 + 3] = fmaxf(fmaf(y23.y, a1s[c8 + 3], a1sh[c8 + 3]), 0.f);
      ab[g][c8 + 4] = fmaxf(fmaf(y45.x, a1s[c8 + 4], a1sh[c8 + 4]), 0.f);
      ab[g][c8 + 5] = fmaxf(fmaf(y45.y, a1s[c8 + 5], a1sh[c8 + 5]), 0.f);
      ab[g][c8 + 6] = fmaxf(fmaf(y67.x, a1s[c8 + 6], a1sh[c8 + 6]), 0.f);
      ab[g][c8 + 7] = fmaxf(fmaf(y67.y, a1s[c8 + 7], a1sh[c8 + 7]), 0.f);
    }
    __builtin_amdgcn_wave_barrier();
    if (val) {
      float z0 = b2s[c4], z1 = b2s[c4 + 1], z2 = b2s[c4 + 2], z3 = b2s[c4 + 3];
#pragma unroll
      for (int k = 0; k < HH2; ++k) {
        float ak = ab[g][k];
        const float* wr = &w2s[k * HH + c4];
        z0 = fmaf(ak, wr[0], z0); z1 = fmaf(ak, wr[1], z1);
        z2 = fmaf(ak, wr[2], z2); z3 = fmaf(ak, wr[3], z3);
      }
      __half2 zh01 = __floats2half2_rn(z0, z1);
      __half2 zh23 = __floats2half2_rn(z2, z3);
      uint2 pack;
      pack.x = *(unsigned int*)&zh01; pack.y = *(unsigned int*)&zh23;
      *(uint2*)&hbuf[n * HH + c4] = pack;
      float2 zf01 = __half22float2(zh01), zf23 = __half22float2(zh23);
      sa0 += zf01.x; sq0 += zf01.x * zf01.x;
      sa1 += zf01.y; sq1 += zf01.y * zf01.y;
      sa2 += zf23.x; sq2 += zf23.x * zf23.x;
      sa3 += zf23.y; sq3 += zf23.y * zf23.y;
    }
    __builtin_amdgcn_wave_barrier();
  }
#define RED(v) v += __shfl_xor(v, 8); v += __shfl_xor(v, 16); v += __shfl_xor(v, 32);
  RED(sa0) RED(sa1) RED(sa2) RED(sa3)
  RED(sq0) RED(sq1) RED(sq2) RED(sq3)
#undef RED
  if ((t & 63) < 8) {
    atomicAdd(&ps[c4], sa0); atomicAdd(&ps[c4 + 1], sa1);
    atomicAdd(&ps[c4 + 2], sa2); atomicAdd(&ps[c4 + 3], sa3);
    atomicAdd(&pq[c4], sq0); atomicAdd(&pq[c4 + 1], sq1);
    atomicAdd(&pq[c4 + 2], sq2); atomicAdd(&pq[c4 + 3], sq3);
  }
  __syncthreads();
  if (t < HH) atomicAdd(&statsC[l * 64 + t], ps[t]);
  else if (t < HH2) atomicAdd(&statsC[l * 64 + t], pq[t - HH]);
}

// ---------------- output: BN2(last) solve fused + LayerNorm + FULL coalesced write
__global__ void __launch_bounds__(256) k_output(const __half* __restrict__ hbuf,
                                                const float* __restrict__ statsC,
                                                const float* __restrict__ bng,
                                                const float* __restrict__ bnb,
                                                const float* __restrict__ lng,
                                                const float* __restrict__ lnb,
                                                float* __restrict__ out) {
  __shared__ float nrb[16 * 33];
  __shared__ float affs[HH], affsh[HH];
  int t = threadIdx.x;
  if (t < HH) {
    float sum = statsC[(NL - 1) * 64 + t], sq = statsC[(NL - 1) * 64 + 32 + t];
    float mean = sum / (float)NNODE;
    float var = fmaxf(sq / (float)NNODE - mean * mean, 0.f);
    float s = bng[(NL - 1) * HH + t] * rsqrtf(var + BNEPS);
    affs[t] = s; affsh[t] = bnb[(NL - 1) * HH + t] - mean * s;
  }
  __syncthreads();
  int gi = blockIdx.x;
  int g = gi >> 8, i = gi & 255;
  int jlo = (i - KBW > 0) ? i - KBW : 0;
  int jhi = (i + KBW < NNN - 1) ? i + KBW : NNN - 1;
  int cnt = jhi - jlo;
  int Ai = (i <= 8) ? i * (i - 1) / 2 : 28 + 8 * (i - 8);
  int Bi = (i <= 248) ? 8 * i : 2012 - (256 - i) * (255 - i) / 2;
  int nb = g * PGN + Ai + Bi;
  int r = t >> 5, c = t & 31;
  float sc = affs[c], sh = affsh[c];
  float lg = lng[c], lb = lnb[c];
  for (int rr = r; rr < cnt; rr += 8) {
    float v = fmaf(__half2float(hbuf[(nb + rr) * HH + c]), sc, sh);
    float s = v;
#pragma unroll
    for (int off = 16; off > 0; off >>= 1) s += __shfl_xor(s, off, 32);
    float mean = s * (1.f / 32.f);
    float d = v - mean;
    float q = d * d;
#pragma unroll
    for (int off = 16; off > 0; off >>= 1) q += __shfl_xor(q, off, 32);
    float var = q * (1.f / 32.f);
    nrb[rr * 33 + c] = d * rsqrtf(var + BNEPS) * lg + lb;
  }
  __syncthreads();
  int j = t;
  bool valid = (j >= jlo) & (j <= jhi) & (j != i);
  int rr = j - jlo - ((j > i) ? 1 : 0);
  rr = (rr < 0) ? 0 : ((rr > 15) ? 15 : rr);
  size_t ob = (((size_t)g * HH) * NNN + i) * NNN + j;
#pragma unroll
  for (int h = 0; h < HH; ++h) {
    float val = valid ? nrb[rr * 33 + h] : 0.f;
    __builtin_nontemporal_store(val, &out[ob + (size_t)h * NNN * NNN]);
  }
}

extern "C" void kernel_launch(void* const* d_in, const int* in_sizes, int n_in,
                              void* d_out, int out_size, void* d_ws, size_t ws_size,
                              hipStream_t stream) {
  (void)in_sizes; (void)n_in;
  const float* x3d   = (const float*)d_in[0];
  const float* eattr = (const float*)d_in[1];
  const int*   eidx  = (const int*)d_in[2];
  const float* wlen = (const float*)d_in[5];
  const float* blen = (const float*)d_in[6];
  const float* wang = (const float*)d_in[7];
  const float* bang = (const float*)d_in[8];
  const float* w1g  = (const float*)d_in[9];
  const float* b1g  = (const float*)d_in[10];
  const float* g1   = (const float*)d_in[11];
  const float* bb1  = (const float*)d_in[12];
  const float* w2g  = (const float*)d_in[13];
  const float* b2g  = (const float*)d_in[14];
  const float* epsg = (const float*)d_in[15];
  const float* bng  = (const float*)d_in[16];
  const float* bnb  = (const float*)d_in[17];
  const float* lng  = (const float*)d_in[18];
  const float* lnb  = (const float*)d_in[19];
  float* out = (float*)d_out;

  char* ws = (char*)d_ws;
  size_t off = 0;
  auto alloc = [&](size_t bytes) {
    void* p = ws + off;
    off += (bytes + 255) & ~(size_t)255;
    return p;
  };
  unsigned int* pk  = (unsigned int*)alloc((size_t)NEDGE * 4);
  int*   rowptr     = (int*)alloc((size_t)(NNODE + 1) * 4);
  int*   counts     = (int*)alloc((size_t)NNODE * 4);
  float* statsA     = (float*)alloc((NL * 128 + NL * 64) * 4);
  float* statsC     = statsA + NL * 128;
  int*   cursor     = (int*)alloc((size_t)NNODE * 4);
  __half* hbuf      = (__half*)alloc((size_t)NNODE * HH * 2);
  __half* y1buf     = (__half*)alloc((size_t)NNODE * HH2 * 2);
  __half* tab       = (__half*)alloc((size_t)TTAB * HH * 2);
  int*   bsum       = (int*)alloc(503 * 4);
  int*   boff       = (int*)alloc(503 * 4);

  if (off > ws_size) {
    hipMemsetAsync(d_out, 0x7F, (size_t)out_size * 4, stream);
    return;
  }

  hipMemsetAsync(counts, 0, (size_t)NNODE * 4 + (NL * 128 + NL * 64) * 4, stream);

  k_prep<<<EMB_BLKS + TAB_BLKS + HIST_BLKS, 256, 0, stream>>>(x3d, wlen, blen, wang, bang,
                                                              eidx + NEDGE, hbuf, tab, counts);
  k_scan1<<<NNODE / 256, 256, 0, stream>>>(counts, bsum);
  k_scan2<<<1, 512, 0, stream>>>(bsum, boff);
  k_scan3<<<NNODE / 256, 256, 0, stream>>>(counts, boff, rowptr, cursor);
  k_scatter<<<8048, 256, 0, stream>>>(eidx, eidx + NEDGE, eattr, cursor, pk);

  for (int l = 0; l < NL; ++l) {
    int relu = l >= 1 ? 1 : 0;
    k_layerA<<<2048, 256, 0, stream>>>(hbuf, rowptr, pk, tab, statsC, bng, bnb,
                                       w1g, b1g, epsg, y1buf, statsA, l, relu);
    k_layerC<<<2048, 256, 0, stream>>>(y1buf, statsA, g1, bb1, w2g, b2g, hbuf, statsC, l);
  }

  k_output<<<NNN * 32, 256, 0, stream>>>(hbuf, statsC, bng, bnb, lng, lnb, out);
}

// Round 15
// 930.154 us; speedup vs baseline: 1.4702x; 1.0167x over previous
//
#include <hip/hip_runtime.h>
#include <hip/hip_bf16.h>
#include <hip/hip_fp16.h>

#define HH 32
#define HH2 64
#define NRBF_ 20
#define NL 5
#define NNN 256
#define KBW 8
#define PGN 4024
#define TTAB 4096
constexpr int NNODE = 128768;
constexpr int NEDGE = 2060288;
constexpr float BNEPS = 1e-5f;
constexpr float PI_F = 3.14159265358979323846f;

#define EMB_BLKS (NNODE * HH / 256)      // 16096
#define TAB_BLKS (TTAB * HH / 256)       // 512
#define HIST_BLKS (NEDGE / 256)          // 8048

typedef _Float16 h2v __attribute__((ext_vector_type(2)));

union U32H2 { unsigned int u; h2v v; };

__device__ __forceinline__ h2v u2h(unsigned int u) { U32H2 x; x.u = u; return x.v; }

__device__ __forceinline__ h2v hmax2v(h2v a, h2v b) {
#if __has_builtin(__builtin_elementwise_max)
  return __builtin_elementwise_max(a, b);
#else
  h2v r; r.x = a.x > b.x ? a.x : b.x; r.y = a.y > b.y ? a.y : b.y; return r;
#endif
}

__device__ __forceinline__ float fdot2f(h2v a, h2v b, float c) {
#if __has_builtin(__builtin_amdgcn_fdot2)
  return __builtin_amdgcn_fdot2(a, b, c, false);
#else
  return fmaf((float)a.x, (float)b.x, fmaf((float)a.y, (float)b.y, c));
#endif
}

// ---------------- fused prep: node embed | ea table | dst histogram
__global__ void __launch_bounds__(256) k_prep(const float* __restrict__ x3d,
                                              const float* __restrict__ wlen,
                                              const float* __restrict__ blen,
                                              const float* __restrict__ wang,
                                              const float* __restrict__ bang,
                                              const int* __restrict__ dst,
                                              __half* __restrict__ hbuf,
                                              __half* __restrict__ tab,
                                              int* __restrict__ counts) {
  int b = blockIdx.x;
  int t = threadIdx.x;
  if (b < EMB_BLKS) {
    __shared__ float wl[NRBF_ * HH];
    __shared__ float bl[HH];
    for (int j = t; j < NRBF_ * HH; j += 256) wl[j] = wlen[j];
    if (t < HH) bl[t] = blen[t];
    __syncthreads();
    int idx = b * 256 + t;
    int n = idx >> 5, c = idx & 31;
    float x = x3d[n];
    float acc = bl[c];
#pragma unroll
    for (int k = 0; k < NRBF_; ++k) {
      float d = x - 0.1f * (float)k;
      acc = fmaf(__expf(-10.f * d * d), wl[k * HH + c], acc);
    }
    hbuf[idx] = __float2half(acc);
  } else if (b < EMB_BLKS + TAB_BLKS) {
    __shared__ float wa[NRBF_ * HH];
    __shared__ float ba[HH];
    for (int j = t; j < NRBF_ * HH; j += 256) wa[j] = wang[j];
    if (t < HH) ba[t] = bang[t];
    __syncthreads();
    int idx = (b - EMB_BLKS) * 256 + t;
    int row = idx >> 5, c = idx & 31;
    float ang = (float)row * (PI_F / (float)(TTAB - 1));
    const float step = PI_F / 19.f;
    float acc = ba[c];
#pragma unroll
    for (int k = 0; k < NRBF_; ++k) {
      float d = ang - step * (float)k;
      acc = fmaf(__expf(-10.f * d * d), wa[k * HH + c], acc);
    }
    tab[row * HH + c] = __float2half(acc);
  } else {
    int e = (b - EMB_BLKS - TAB_BLKS) * 256 + t;
    atomicAdd(&counts[dst[e]], 1);
  }
}

// ---------------- scan step 1 (503 blocks x 256)
__global__ void __launch_bounds__(256) k_scan1(const int* __restrict__ counts, int* __restrict__ bsum) {
  __shared__ int sd[256];
  int t = threadIdx.x;
  sd[t] = counts[blockIdx.x * 256 + t];
  __syncthreads();
  for (int s = 128; s > 0; s >>= 1) { if (t < s) sd[t] += sd[t + s]; __syncthreads(); }
  if (t == 0) bsum[blockIdx.x] = sd[0];
}

// ---------------- scan step 2
__global__ void __launch_bounds__(512) k_scan2(const int* __restrict__ bsum, int* __restrict__ boff) {
  __shared__ int sd[512];
  int t = threadIdx.x;
  int v = (t < 503) ? bsum[t] : 0;
  sd[t] = v;
  __syncthreads();
  for (int off = 1; off < 512; off <<= 1) {
    int x = (t >= off) ? sd[t - off] : 0;
    __syncthreads();
    sd[t] += x;
    __syncthreads();
  }
  if (t < 503) boff[t] = sd[t] - v;
}

// ---------------- scan step 3: rowptr + per-node cursor
__global__ void __launch_bounds__(256) k_scan3(const int* __restrict__ counts, const int* __restrict__ boff,
                                               int* __restrict__ rowptr, int* __restrict__ cursor) {
  __shared__ int sd[256];
  int t = threadIdx.x;
  int i = blockIdx.x * 256 + t;
  int v = counts[i];
  sd[t] = v;
  __syncthreads();
  for (int off = 1; off < 256; off <<= 1) {
    int x = (t >= off) ? sd[t - off] : 0;
    __syncthreads();
    sd[t] += x;
    __syncthreads();
  }
  int excl = sd[t] - v + boff[blockIdx.x];
  rowptr[i] = excl;
  cursor[i] = excl;
  if (i == NNODE - 1) rowptr[NNODE] = excl + v;
}

// ---------------- XCD-range-exclusive scatter; packs src(17b) | tab-idx(12b) into 4B
__global__ void __launch_bounds__(256) k_scatter(const int* __restrict__ srcA,
                                                 const int* __restrict__ dstA,
                                                 const float* __restrict__ eattr,
                                                 int* __restrict__ cursor,
                                                 unsigned int* __restrict__ pk) {
  const float angsc = (float)(TTAB - 1) / PI_F;
  int bid = blockIdx.x;
  int x = bid & 7;
  int j = bid >> 3;
  int lo = x * (NNODE / 8);
  int hi = lo + (NNODE / 8);
  int e0 = j * 2048 + threadIdx.x;
#pragma unroll
  for (int k = 0; k < 8; ++k) {
    int e = e0 + k * 256;
    int d = dstA[e];
    if (d >= lo && d < hi) {
      int pos = atomicAdd(&cursor[d], 1);
      unsigned int idx = min((unsigned int)fmaf(eattr[e], angsc, 0.5f), (unsigned int)(TTAB - 1));
      pk[pos] = (unsigned int)srcA[e] | (idx << 17);
    }
  }
}

// ---------------- edge batch: 8 edges, packed-fp16 math, fdot2 per-channel accumulate
template<bool MASK>
__device__ __forceinline__ void edge_batch(const __half* __restrict__ hbuf,
                                           const __half* __restrict__ tab,
                                           unsigned int myq, int p, int p1, int c4,
                                           h2v sc01, h2v sh01,
                                           h2v sc23, h2v sh23, h2v lo2,
                                           float& a0, float& a1, float& a2, float& a3) {
  unsigned int qv[8];
  uint2 Hv[8], Ev[8];
#pragma unroll
  for (int i = 0; i < 8; ++i) qv[i] = (unsigned int)__shfl((int)myq, i, 8);
#pragma unroll
  for (int i = 0; i < 8; ++i) {
    Hv[i] = *(const uint2*)&hbuf[(qv[i] & 0x1FFFF) * HH + c4];
    Ev[i] = *(const uint2*)&tab[(qv[i] >> 17) * HH + c4];
  }
  const h2v selA = {(_Float16)1.f, (_Float16)0.f};
  const h2v selB = {(_Float16)0.f, (_Float16)1.f};
  const h2v zz   = {(_Float16)0.f, (_Float16)0.f};
#pragma unroll
  for (int i = 0; i < 8; ++i) {
    h2v mkA = selA, mkB = selB;
    if (MASK) {
      bool ok = (p + i) < p1;
      mkA = ok ? selA : zz;
      mkB = ok ? selB : zz;
    }
    h2v h01 = u2h(Hv[i].x), h23 = u2h(Hv[i].y);
    h2v e01 = u2h(Ev[i].x), e23 = u2h(Ev[i].y);
    h2v m01 = hmax2v(hmax2v(h01 * sc01 + sh01, lo2) + e01, zz);
    h2v m23 = hmax2v(hmax2v(h23 * sc23 + sh23, lo2) + e23, zz);
    a0 = fdot2f(m01, mkA, a0);
    a1 = fdot2f(m01, mkB, a1);
    a2 = fdot2f(m23, mkA, a2);
    a3 = fdot2f(m23, mkB, a3);
  }
}

// ---------------- layerA: 8-lane groups, 4 ch/lane, packed-fp16 + shfl-pk
__global__ void __launch_bounds__(256) k_layerA(const __half* __restrict__ hbuf,
                                                const int* __restrict__ rowptr,
                                                const unsigned int* __restrict__ pk,
                                                const __half* __restrict__ tab,
                                                const float* __restrict__ statsC,
                                                const float* __restrict__ bng,
                                                const float* __restrict__ bnb,
                                                const float* __restrict__ w1g,
                                                const float* __restrict__ b1g,
                                                const float* __restrict__ epsg,
                                                __half* __restrict__ y1buf,
                                                float* __restrict__ statsA,
                                                int l, int relu) {
  __shared__ float w1s[HH * HH2];
  __shared__ float b1s[HH2];
  __shared__ float affs[HH], affsh[HH];
  __shared__ float tb[32][HH + 1];
  __shared__ float ps[HH2], pq[HH2];
  int t = threadIdx.x;
  const float* w1l = w1g + l * HH * HH2;
  for (int j = t; j < HH * HH2; j += 256) w1s[j] = w1l[j];
  if (t < HH2) { b1s[t] = b1g[l * HH2 + t]; ps[t] = 0.f; pq[t] = 0.f; }
  if (t < HH) {
    if (l == 0) { affs[t] = 1.f; affsh[t] = 0.f; }
    else {
      float sum = statsC[(l - 1) * 64 + t], sq = statsC[(l - 1) * 64 + 32 + t];
      float mean = sum / (float)NNODE;
      float var = fmaxf(sq / (float)NNODE - mean * mean, 0.f);
      float s = bng[(l - 1) * HH + t] * rsqrtf(var + BNEPS);
      affs[t] = s; affsh[t] = bnb[(l - 1) * HH + t] - mean * s;
    }
  }
  int g = t >> 3, c = t & 7;
  int c4 = c * 4, c8 = c * 8;
  float epsv = 1.f + epsg[l];
  float lof = relu ? 0.f : -60000.f;   // fp16-representable lower bound when no relu
  float sA0 = 0.f, sA1 = 0.f, sA2 = 0.f, sA3 = 0.f, sA4 = 0.f, sA5 = 0.f, sA6 = 0.f, sA7 = 0.f;
  float sQ0 = 0.f, sQ1 = 0.f, sQ2 = 0.f, sQ3 = 0.f, sQ4 = 0.f, sQ5 = 0.f, sQ6 = 0.f, sQ7 = 0.f;
  __syncthreads();
  float sc0f = affs[c4], sh0f = affsh[c4];
  float sc1f = affs[c4 + 1], sh1f = affsh[c4 + 1];
  float sc2f = affs[c4 + 2], sh2f = affsh[c4 + 2];
  float sc3f = affs[c4 + 3], sh3f = affsh[c4 + 3];
  h2v sc01 = {(_Float16)sc0f, (_Float16)sc1f}, sh01 = {(_Float16)sh0f, (_Float16)sh1f};
  h2v sc23 = {(_Float16)sc2f, (_Float16)sc3f}, sh23 = {(_Float16)sh2f, (_Float16)sh3f};
  h2v lo2 = {(_Float16)lof, (_Float16)lof};
  int stride = gridDim.x * 32;
  int iters = (NNODE + stride - 1) / stride;
  int n = blockIdx.x * 32 + g;
  for (int it = 0; it < iters; ++it, n += stride) {
    bool val = n < NNODE;
    if (val) {
      int p0 = rowptr[n], p1 = rowptr[n + 1];
      uint2 HN = *(const uint2*)&hbuf[n * HH + c4];
      float2 hn01 = __half22float2(*(__half2*)&HN.x);
      float2 hn23 = __half22float2(*(__half2*)&HN.y);
      float a0 = 0.f, a1 = 0.f, a2 = 0.f, a3 = 0.f;
      int p = p0;
      for (; p + 8 <= p1; p += 8) {
        unsigned int myq = __builtin_nontemporal_load(&pk[p + c]);
        edge_batch<false>(hbuf, tab, myq, p, p1, c4, sc01, sh01, sc23, sh23, lo2, a0, a1, a2, a3);
      }
      if (p < p1) {
        int pidx = p + c;
        unsigned int myq = __builtin_nontemporal_load(&pk[pidx < p1 ? pidx : p]);
        edge_batch<true>(hbuf, tab, myq, p, p1, c4, sc01, sh01, sc23, sh23, lo2, a0, a1, a2, a3);
      }
      tb[g][c4]     = fmaf(epsv, fmaxf(fmaf(hn01.x, sc0f, sh0f), lof), a0);
      tb[g][c4 + 1] = fmaf(epsv, fmaxf(fmaf(hn01.y, sc1f, sh1f), lof), a1);
      tb[g][c4 + 2] = fmaf(epsv, fmaxf(fmaf(hn23.x, sc2f, sh2f), lof), a2);
      tb[g][c4 + 3] = fmaf(epsv, fmaxf(fmaf(hn23.y, sc3f, sh3f), lof), a3);
    }
    __builtin_amdgcn_wave_barrier();
    if (val) {
      float y0 = b1s[c8], y1 = b1s[c8 + 1], y2 = b1s[c8 + 2], y3 = b1s[c8 + 3];
      float y4 = b1s[c8 + 4], y5 = b1s[c8 + 5], y6 = b1s[c8 + 6], y7 = b1s[c8 + 7];
#pragma unroll
      for (int k = 0; k < HH; ++k) {
        float tk = tb[g][k];
        const float* wr = &w1s[k * HH2 + c8];
        y0 = fmaf(tk, wr[0], y0); y1 = fmaf(tk, wr[1], y1);
        y2 = fmaf(tk, wr[2], y2); y3 = fmaf(tk, wr[3], y3);
        y4 = fmaf(tk, wr[4], y4); y5 = fmaf(tk, wr[5], y5);
        y6 = fmaf(tk, wr[6], y6); y7 = fmaf(tk, wr[7], y7);
      }
      __half2 h01 = __floats2half2_rn(y0, y1);
      __half2 h23 = __floats2half2_rn(y2, y3);
      __half2 h45 = __floats2half2_rn(y4, y5);
      __half2 h67 = __floats2half2_rn(y6, y7);
      uint4 pack;
      pack.x = *(unsigned int*)&h01; pack.y = *(unsigned int*)&h23;
      pack.z = *(unsigned int*)&h45; pack.w = *(unsigned int*)&h67;
      *(uint4*)&y1buf[n * HH2 + c8] = pack;
      float2 z01 = __half22float2(h01), z23 = __half22float2(h23);
      float2 z45 = __half22float2(h45), z67 = __half22float2(h67);
      sA0 += z01.x; sQ0 += z01.x * z01.x; sA1 += z01.y; sQ1 += z01.y * z01.y;
      sA2 += z23.x; sQ2 += z23.x * z23.x; sA3 += z23.y; sQ3 += z23.y * z23.y;
      sA4 += z45.x; sQ4 += z45.x * z45.x; sA5 += z45.y; sQ5 += z45.y * z45.y;
      sA6 += z67.x; sQ6 += z67.x * z67.x; sA7 += z67.y; sQ7 += z67.y * z67.y;
    }
    __builtin_amdgcn_wave_barrier();
  }
#define RED(v) v += __shfl_xor(v, 8); v += __shfl_xor(v, 16); v += __shfl_xor(v, 32);
  RED(sA0) RED(sA1) RED(sA2) RED(sA3) RED(sA4) RED(sA5) RED(sA6) RED(sA7)
  RED(sQ0) RED(sQ1) RED(sQ2) RED(sQ3) RED(sQ4) RED(sQ5) RED(sQ6) RED(sQ7)
#undef RED
  if ((t & 63) < 8) {
    atomicAdd(&ps[c8], sA0); atomicAdd(&ps[c8 + 1], sA1);
    atomicAdd(&ps[c8 + 2], sA2); atomicAdd(&ps[c8 + 3], sA3);
    atomicAdd(&ps[c8 + 4], sA4); atomicAdd(&ps[c8 + 5], sA5);
    atomicAdd(&ps[c8 + 6], sA6); atomicAdd(&ps[c8 + 7], sA7);
    atomicAdd(&pq[c8], sQ0); atomicAdd(&pq[c8 + 1], sQ1);
    atomicAdd(&pq[c8 + 2], sQ2); atomicAdd(&pq[c8 + 3], sQ3);
    atomicAdd(&pq[c8 + 4], sQ4); atomicAdd(&pq[c8 + 5], sQ5);
    atomicAdd(&pq[c8 + 6], sQ6); atomicAdd(&pq[c8 + 7], sQ7);
  }
  __syncthreads();
  if (t < HH2) {
    atomicAdd(&statsA[l * 128 + t], ps[t]);
    atomicAdd(&statsA[l * 128 + 64 + t], pq[t]);
  }
}

// ---------------- layerC: 8-lane groups; BN1 solve fused; affine->relu->@w2+b2; BN2 stats
__global__ void __launch_bounds__(256) k_layerC(const __half* __restrict__ y1buf,
                                                const float* __restrict__ statsA,
                                                const float* __restrict__ g1,
                                                const float* __restrict__ bb1,
                                                const float* __restrict__ w2g,
                                                const float* __restrict__ b2g,
                                                __half* __restrict__ hbuf,
                                                float* __restrict__ statsC, int l) {
  __shared__ float w2s[HH2 * HH];
  __shared__ float b2s[HH];
  __shared__ float a1s[HH2], a1sh[HH2];
  __shared__ float ab[32][HH2 + 2];
  __shared__ float ps[HH], pq[HH];
  int t = threadIdx.x;
  const float* w2l = w2g + l * HH2 * HH;
  for (int j = t; j < HH2 * HH; j += 256) w2s[j] = w2l[j];
  if (t < HH) { b2s[t] = b2g[l * HH + t]; ps[t] = 0.f; pq[t] = 0.f; }
  if (t < HH2) {
    float sum = statsA[l * 128 + t], sq = statsA[l * 128 + 64 + t];
    float mean = sum / (float)NNODE;
    float var = fmaxf(sq / (float)NNODE - mean * mean, 0.f);
    float s = g1[l * HH2 + t] * rsqrtf(var + BNEPS);
    a1s[t] = s; a1sh[t] = bb1[l * HH2 + t] - mean * s;
  }
  int g = t >> 3, c = t & 7;
  int c8 = c * 8, c4 = c * 4;
  float sa0 = 0.f, sq0 = 0.f, sa1 = 0.f, sq1 = 0.f;
  float sa2 = 0.f, sq2 = 0.f, sa3 = 0.f, sq3 = 0.f;
  __syncthreads();
  int stride = gridDim.x * 32;
  int iters = (NNODE + stride - 1) / stride;
  int n = blockIdx.x * 32 + g;
  for (int it = 0; it < iters; ++it, n += stride) {
    bool val = n < NNODE;
    if (val) {
      uint4 Y = *(const uint4*)&y1buf[n * HH2 + c8];
      float2 y01 = __half22float2(*(__half2*)&Y.x);
      float2 y23 = __half22float2(*(__half2*)&Y.y);
      float2 y45 = __half22float2(*(__half2*)&Y.z);
      float2 y67 = __half22float2(*(__half2*)&Y.w);
      ab[g][c8]     = fmaxf(fmaf(y01.x, a1s[c8],     a1sh[c8]),     0.f);
      ab[g][c8 + 1] = fmaxf(fmaf(y01.y, a1s[c8 + 1], a1sh[c8 + 1]), 0.f);
      ab[g][c8 + 2] = fmaxf(fmaf(y23.x, a1s[c8 + 2], a1sh[c8 + 2]), 0.f);
      ab[g][c8 + 3] = fmaxf(fmaf(y23.y, a1s[c8 + 3], a1sh[c8 + 3]), 0.f);
      ab[g][c8 + 4] = fmaxf(fmaf(y45.x, a1s[c8 + 4], a1sh[c8 + 4]), 0.f);
      ab[g][c8 + 5] = fmaxf(fmaf(y45.y, a1s[c8 + 5], a1sh[c8 + 5]), 0.f);
      ab[g][c8 + 6] = fmaxf(fmaf(y67.x, a1s[c8 + 6], a1sh[c8 + 6]), 0.f);
      ab[g][c8 + 7] = fmaxf(fmaf(y67.y, a1s[c8 + 7], a1sh[c8 + 7]), 0.f);
    }
    __builtin_amdgcn_wave_barrier();
    if (val) {
      float z0 = b2s[c4], z1 = b2s[c4 + 1], z2 = b2s[c4 + 2], z3 = b2s[c4 + 3];
#pragma unroll
      for (int k = 0; k < HH2; ++k) {
        float ak = ab[g][k];
        const float* wr = &w2s[k * HH + c4];
        z0 = fmaf(ak, wr[0], z0); z1 = fmaf(ak, wr[1], z1);
        z2 = fmaf(ak, wr[2], z2); z3 = fmaf(ak, wr[3], z3);
      }
      __half2 zh01 = __floats2half2_rn(z0, z1);
      __half2 zh23 = __floats2half2_rn(z2, z3);
      uint2 pack;
      pack.x = *(unsigned int*)&zh01; pack.y = *(unsigned int*)&zh23;
      *(uint2*)&hbuf[n * HH + c4] = pack;
      float2 zf01 = __half22float2(zh01), zf23 = __half22float2(zh23);
      sa0 += zf01.x; sq0 += zf01.x * zf01.x;
      sa1 += zf01.y; sq1 += zf01.y * zf01.y;
      sa2 += zf23.x; sq2 += zf23.x * zf23.x;
      sa3 += zf23.y; sq3 += zf23.y * zf23.y;
    }
    __builtin_amdgcn_wave_barrier();
  }
#define RED(v) v += __shfl_xor(v, 8); v += __shfl_xor(v, 16); v += __shfl_xor(v, 32);
  RED(sa0) RED(sa1) RED(sa2) RED(sa3)
  RED(sq0) RED(sq1) RED(sq2) RED(sq3)
#undef RED
  if ((t & 63) < 8) {
    atomicAdd(&ps[c4], sa0); atomicAdd(&ps[c4 + 1], sa1);
    atomicAdd(&ps[c4 + 2], sa2); atomicAdd(&ps[c4 + 3], sa3);
    atomicAdd(&pq[c4], sq0); atomicAdd(&pq[c4 + 1], sq1);
    atomicAdd(&pq[c4 + 2], sq2); atomicAdd(&pq[c4 + 3], sq3);
  }
  __syncthreads();
  if (t < HH) atomicAdd(&statsC[l * 64 + t], ps[t]);
  else if (t < HH2) atomicAdd(&statsC[l * 64 + t], pq[t - HH]);
}

// ---------------- output: BN2(last) solve fused + LayerNorm + FULL coalesced write
__global__ void __launch_bounds__(256) k_output(const __half* __restrict__ hbuf,
                                                const float* __restrict__ statsC,
                                                const float* __restrict__ bng,
                                                const float* __restrict__ bnb,
                                                const float* __restrict__ lng,
                                                const float* __restrict__ lnb,
                                                float* __restrict__ out) {
  __shared__ float nrb[16 * 33];
  __shared__ float affs[HH], affsh[HH];
  int t = threadIdx.x;
  if (t < HH) {
    float sum = statsC[(NL - 1) * 64 + t], sq = statsC[(NL - 1) * 64 + 32 + t];
    float mean = sum / (float)NNODE;
    float var = fmaxf(sq / (float)NNODE - mean * mean, 0.f);
    float s = bng[(NL - 1) * HH + t] * rsqrtf(var + BNEPS);
    affs[t] = s; affsh[t] = bnb[(NL - 1) * HH + t] - mean * s;
  }
  __syncthreads();
  int gi = blockIdx.x;
  int g = gi >> 8, i = gi & 255;
  int jlo = (i - KBW > 0) ? i - KBW : 0;
  int jhi = (i + KBW < NNN - 1) ? i + KBW : NNN - 1;
  int cnt = jhi - jlo;
  int Ai = (i <= 8) ? i * (i - 1) / 2 : 28 + 8 * (i - 8);
  int Bi = (i <= 248) ? 8 * i : 2012 - (256 - i) * (255 - i) / 2;
  int nb = g * PGN + Ai + Bi;
  int r = t >> 5, c = t & 31;
  float sc = affs[c], sh = affsh[c];
  float lg = lng[c], lb = lnb[c];
  for (int rr = r; rr < cnt; rr += 8) {
    float v = fmaf(__half2float(hbuf[(nb + rr) * HH + c]), sc, sh);
    float s = v;
#pragma unroll
    for (int off = 16; off > 0; off >>= 1) s += __shfl_xor(s, off, 32);
    float mean = s * (1.f / 32.f);
    float d = v - mean;
    float q = d * d;
#pragma unroll
    for (int off = 16; off > 0; off >>= 1) q += __shfl_xor(q, off, 32);
    float var = q * (1.f / 32.f);
    nrb[rr * 33 + c] = d * rsqrtf(var + BNEPS) * lg + lb;
  }
  __syncthreads();
  int j = t;
  bool valid = (j >= jlo) & (j <= jhi) & (j != i);
  int rr = j - jlo - ((j > i) ? 1 : 0);
  rr = (rr < 0) ? 0 : ((rr > 15) ? 15 : rr);
  size_t ob = (((size_t)g * HH) * NNN + i) * NNN + j;
#pragma unroll
  for (int h = 0; h < HH; ++h) {
    float val = valid ? nrb[rr * 33 + h] : 0.f;
    __builtin_nontemporal_store(val, &out[ob + (size_t)h * NNN * NNN]);
  }
}

extern "C" void kernel_launch(void* const* d_in, const int* in_sizes, int n_in,
                              void* d_out, int out_size, void* d_ws, size_t ws_size,
                              hipStream_t stream) {
  (void)in_sizes; (void)n_in;
  const float* x3d   = (const float*)d_in[0];
  const float* eattr = (const float*)d_in[1];
  const int*   eidx  = (const int*)d_in[2];
  const float* wlen = (const float*)d_in[5];
  const float* blen = (const float*)d_in[6];
  const float* wang = (const float*)d_in[7];
  const float* bang = (const float*)d_in[8];
  const float* w1g  = (const float*)d_in[9];
  const float* b1g  = (const float*)d_in[10];
  const float* g1   = (const float*)d_in[11];
  const float* bb1  = (const float*)d_in[12];
  const float* w2g  = (const float*)d_in[13];
  const float* b2g  = (const float*)d_in[14];
  const float* epsg = (const float*)d_in[15];
  const float* bng  = (const float*)d_in[16];
  const float* bnb  = (const float*)d_in[17];
  const float* lng  = (const float*)d_in[18];
  const float* lnb  = (const float*)d_in[19];
  float* out = (float*)d_out;

  char* ws = (char*)d_ws;
  size_t off = 0;
  auto alloc = [&](size_t bytes) {
    void* p = ws + off;
    off += (bytes + 255) & ~(size_t)255;
    return p;
  };
  unsigned int* pk  = (unsigned int*)alloc((size_t)NEDGE * 4);
  int*   rowptr     = (int*)alloc((size_t)(NNODE + 1) * 4);
  int*   counts     = (int*)alloc((size_t)NNODE * 4);
  float* statsA     = (float*)alloc((NL * 128 + NL * 64) * 4);
  float* statsC     = statsA + NL * 128;
  int*   cursor     = (int*)alloc((size_t)NNODE * 4);
  __half* hbuf      = (__half*)alloc((size_t)NNODE * HH * 2);
  __half* y1buf     = (__half*)alloc((size_t)NNODE * HH2 * 2);
  __half* tab       = (__half*)alloc((size_t)TTAB * HH * 2);
  int*   bsum       = (int*)alloc(503 * 4);
  int*   boff       = (int*)alloc(503 * 4);

  if (off > ws_size) {
    hipMemsetAsync(d_out, 0x7F, (size_t)out_size * 4, stream);
    return;
  }

  hipMemsetAsync(counts, 0, (size_t)NNODE * 4 + (NL * 128 + NL * 64) * 4, stream);

  k_prep<<<EMB_BLKS + TAB_BLKS + HIST_BLKS, 256, 0, stream>>>(x3d, wlen, blen, wang, bang,
                                                              eidx + NEDGE, hbuf, tab, counts);
  k_scan1<<<NNODE / 256, 256, 0, stream>>>(counts, bsum);
  k_scan2<<<1, 512, 0, stream>>>(bsum, boff);
  k_scan3<<<NNODE / 256, 256, 0, stream>>>(counts, boff, rowptr, cursor);
  k_scatter<<<8048, 256, 0, stream>>>(eidx, eidx + NEDGE, eattr, cursor, pk);

  for (int l = 0; l < NL; ++l) {
    int relu = l >= 1 ? 1 : 0;
    k_layerA<<<2048, 256, 0, stream>>>(hbuf, rowptr, pk, tab, statsC, bng, bnb,
                                       w1g, b1g, epsg, y1buf, statsA, l, relu);
    k_layerC<<<2048, 256, 0, stream>>>(y1buf, statsA, g1, bb1, w2g, b2g, hbuf, statsC, l);
  }

  k_output<<<NNN * 32, 256, 0, stream>>>(hbuf, statsC, bng, bnb, lng, lnb, out);
}